// Round 1
// baseline (249.177 us; speedup 1.0000x reference)
//
#include <hip/hip_runtime.h>
#include <hip/hip_bf16.h>
#include <math.h>

#define NN 1024
#define LDIM 32
#define HDIM 64

// ---------------- fp32 workspace layout (float offsets) ----------------
#define WS_SELF 0                        // N*L   self_term [i][l]
#define WS_AA   (WS_SELF + NN*LDIM)      // N*H   a_i [i][h]  (pre-scaled by 2log2e)
#define WS_CI   (WS_AA   + NN*HDIM)      // N*L   -log2e*(ci+bc) [i][l]
#define WS_AGG  (WS_CI   + NN*LDIM)      // N     sigmoid(aggr)
#define WS_BI2  (WS_AGG  + NN)           // H     bi2 * 2log2e
#define WS_BI3  (WS_BI2  + HDIM)         // L     bi3 (unscaled)
#define WS_FEND (WS_BI3  + LDIM)

// ---------------- bf16(u16) region (short offsets from wsu) -------------
#define U_BJB  0                         // N*H   b_j [j][h]  (pre-scaled by 2log2e)
#define U_HJB  (U_BJB + NN*HDIM)         // N*L   h   [j][l]
#define U_JT   (U_HJB + NN*LDIM)         // N*16*8 paired {h0,h1}{cj0,cj1}{pc0,pc1}{ps0,ps1}
#define U_W2B  (U_JT  + NN*LDIM*4)       // H*H   Wi2 [n][k] * 2log2e
#define U_W3B  (U_W2B + HDIM*HDIM)       // L*H   Wi3 [l][k] (unscaled)
#define U_END  (U_W3B + LDIM*HDIM)

// packed-pair transposed weight tables in precompute LDS (uint offsets)
#define PK_W1  0        // 16*64   Ws1
#define PK_W2  1024     // 32*64   Ws2
#define PK_W3  3072     // 32*32   Ws3
#define PK_WI1 4096     // 64*64   Wi1
#define PK_WC  8192     // 32*32   Wc
#define PK_END 9216     // 36 KB

#define K2P  2.88539008f     // 2*log2(e)
#define K1N  (-1.44269504f)  // -log2(e)

typedef __attribute__((ext_vector_type(8))) short bf16x8;
typedef __attribute__((ext_vector_type(4))) float f32x4;
typedef __attribute__((ext_vector_type(2))) float v2f;

__device__ __forceinline__ float fast_rcp(float x) { return __builtin_amdgcn_rcpf(x); }
__device__ __forceinline__ float fast_tanh(float x) {          // full version (precompute)
    float e = __builtin_amdgcn_exp2f(x * K2P);
    return 1.0f - 2.0f * fast_rcp(e + 1.0f);
}
__device__ __forceinline__ float fast_sigmoid(float x) {       // full version (precompute)
    return fast_rcp(1.0f + __builtin_amdgcn_exp2f(x * K1N));
}
__device__ __forceinline__ float blo(unsigned int u) { union { unsigned int i; float f; } v; v.i = u << 16; return v.f; }
__device__ __forceinline__ float bhi(unsigned int u) { union { unsigned int i; float f; } v; v.i = u & 0xffff0000u; return v.f; }
__device__ __forceinline__ float bf2f(unsigned short u) { union { unsigned int i; float f; } v; v.i = ((unsigned int)u) << 16; return v.f; }
__device__ __forceinline__ unsigned short f2bf(float f) {
    __hip_bfloat16 b = __float2bfloat16(f);
    unsigned short u; __builtin_memcpy(&u, &b, 2); return u;
}
__device__ __forceinline__ unsigned int pk2(float a, float b) {
    float2 t; t.x = a; t.y = b;
    __hip_bfloat162 h = __float22bfloat162_rn(t);
    unsigned int u; __builtin_memcpy(&u, &h, 4); return u;
}

// paired tanh of pre-scaled inputs: one rcp for two lanes of work.
// t_k = 1 - 2*rcp(exp2(xp_k)+1); shared rcp via rr = rcp(d0*d1).
__device__ __forceinline__ v2f tanh2_pre(v2f xp) {
    v2f e; e.x = __builtin_amdgcn_exp2f(xp.x); e.y = __builtin_amdgcn_exp2f(xp.y);
    v2f d = e + 1.0f;
    float rr = fast_rcp(d.x * d.y);
    v2f sw; sw.x = d.y; sw.y = d.x;
    v2f r = sw * rr;                 // r_k = rcp(d_k)
    return 1.0f - 2.0f * r;
}

// ------------- kernel 1: precompute (weights packed in-block) -------------
__global__ __launch_bounds__(256) void precompute(
    const float* __restrict__ state,
    const float* __restrict__ Ws1, const float* __restrict__ bs1,
    const float* __restrict__ Ws2, const float* __restrict__ bs2,
    const float* __restrict__ Ws3, const float* __restrict__ bs3,
    const float* __restrict__ Wi1, const float* __restrict__ bi1,
    const float* __restrict__ Wi2, const float* __restrict__ bi2,
    const float* __restrict__ Wi3, const float* __restrict__ bi3,
    const float* __restrict__ phw, const float* __restrict__ Wc,
    const float* __restrict__ bc,  const float* __restrict__ aggr,
    float* __restrict__ ws, unsigned short* __restrict__ wsu) {
    const int tid = threadIdx.x;
    const int w = tid >> 6, t = tid & 63;
    const int i = blockIdx.x * 4 + w;

    __shared__ unsigned int wlds[PK_END];
    __shared__ float shh[4][32], shdh[4][32], sht1[4][64], sht2[4][64];
    __shared__ float shph[4];

    {
        const float2* s1 = (const float2*)Ws1;
        #pragma unroll
        for (int r = 0; r < 4; r++) { int e = tid + r * 256; int f = e >> 4, k2 = e & 15;
            float2 v = s1[e]; wlds[PK_W1 + k2 * 64 + f] = pk2(v.x, v.y); }
        const float2* s2 = (const float2*)Ws2;
        #pragma unroll
        for (int r = 0; r < 8; r++) { int e = tid + r * 256; int f = e >> 5, k2 = e & 31;
            float2 v = s2[e]; wlds[PK_W2 + k2 * 64 + f] = pk2(v.x, v.y); }
        const float2* s3 = (const float2*)Ws3;
        #pragma unroll
        for (int r = 0; r < 4; r++) { int e = tid + r * 256; int f = e >> 5, k2 = e & 31;
            float2 v = s3[e]; wlds[PK_W3 + k2 * 32 + f] = pk2(v.x, v.y); }
        const float2* si = (const float2*)Wi1;
        #pragma unroll
        for (int r = 0; r < 16; r++) { int e = tid + r * 256; int f = e >> 6, c2 = e & 63;
            float2 v = si[e]; wlds[PK_WI1 + c2 * 64 + f] = pk2(v.x, v.y); }
        const float2* sc = (const float2*)Wc;
        #pragma unroll
        for (int r = 0; r < 4; r++) { int e = tid + r * 256; int f = e >> 5, c2 = e & 31;
            float2 v = sc[e]; wlds[PK_WC + c2 * 32 + f] = pk2(v.x, v.y); }
    }
    if (blockIdx.x == 0) {
        #pragma unroll
        for (int r = 0; r < 16; r++) { int e = tid + r * 256; wsu[U_W2B + e] = f2bf(Wi2[e] * K2P); }
        #pragma unroll
        for (int r = 0; r < 8; r++)  { int e = tid + r * 256; wsu[U_W3B + e] = f2bf(Wi3[e]); }
        if (tid < HDIM) ws[WS_BI2 + tid] = bi2[tid] * K2P;
        if (tid < LDIM) ws[WS_BI3 + tid] = bi3[tid];
    }

    float sv = (t < 33) ? state[i * 33 + t] : 0.f;
    if (t < 32) shh[w][t] = sv;
    if (t == 32) shph[w] = sv;
    if (t == 33) ws[WS_AGG + i] = fast_sigmoid(aggr[i]);
    __syncthreads();

    {
        float s = bs1[t];
        const unsigned int* W = wlds + PK_W1;
        #pragma unroll
        for (int k2 = 0; k2 < 16; k2++) {
            unsigned int p = W[k2 * 64 + t];
            s = fmaf(blo(p), shh[w][2 * k2], s);
            s = fmaf(bhi(p), shh[w][2 * k2 + 1], s);
        }
        sht1[w][t] = fast_tanh(s);
    }
    __syncthreads();
    {
        float s = bs2[t];
        const unsigned int* W = wlds + PK_W2;
        #pragma unroll
        for (int k2 = 0; k2 < 32; k2++) {
            unsigned int p = W[k2 * 64 + t];
            s = fmaf(blo(p), sht1[w][2 * k2], s);
            s = fmaf(bhi(p), sht1[w][2 * k2 + 1], s);
        }
        sht2[w][t] = fast_tanh(s);
    }
    __syncthreads();
    if (t < 32) {
        float s = bs3[t];
        const unsigned int* W = wlds + PK_W3;
        #pragma unroll
        for (int k2 = 0; k2 < 32; k2++) {
            unsigned int p = W[k2 * 32 + t];
            s = fmaf(blo(p), sht2[w][2 * k2], s);
            s = fmaf(bhi(p), sht2[w][2 * k2 + 1], s);
        }
        ws[WS_SELF + i * 32 + t] = s;
        shdh[w][t] = s;
    }
    __syncthreads();
    {
        float sa = 0.f, sb = bi1[t];
        const unsigned int* W = wlds + PK_WI1;
        #pragma unroll
        for (int k2 = 0; k2 < 16; k2++) {
            float h0 = shh[w][2 * k2], h1 = shh[w][2 * k2 + 1];
            float d0 = shdh[w][2 * k2], d1 = shdh[w][2 * k2 + 1];
            unsigned int wa  = W[k2 * 64 + t];
            unsigned int wb  = W[(16 + k2) * 64 + t];
            unsigned int wa2 = W[(32 + k2) * 64 + t];
            unsigned int wb2 = W[(48 + k2) * 64 + t];
            sa = fmaf(blo(wa), h0, sa);  sa = fmaf(bhi(wa), h1, sa);
            sb = fmaf(blo(wb), h0, sb);  sb = fmaf(bhi(wb), h1, sb);
            sa = fmaf(blo(wa2), d0, sa); sa = fmaf(bhi(wa2), d1, sa);
            sb = fmaf(blo(wb2), d0, sb); sb = fmaf(bhi(wb2), d1, sb);
        }
        ws[WS_AA + i * 64 + t]  = sa * K2P;          // pre-scaled for tanh_pre
        wsu[U_BJB + i * 64 + t] = f2bf(sb * K2P);
    }
    if (t < 32) {
        float si2 = 0.f, sj = 0.f;
        const unsigned int* W = wlds + PK_WC;
        #pragma unroll
        for (int m2 = 0; m2 < 16; m2++) {
            float h0 = shh[w][2 * m2], h1 = shh[w][2 * m2 + 1];
            unsigned int wi = W[m2 * 32 + t];
            unsigned int wj = W[(16 + m2) * 32 + t];
            si2 = fmaf(blo(wi), h0, si2); si2 = fmaf(bhi(wi), h1, si2);
            sj  = fmaf(blo(wj), h0, sj);  sj  = fmaf(bhi(wj), h1, sj);
        }
        ws[WS_CI + i * 32 + t] = (si2 + bc[t]) * K1N; // pre-scaled for rcp(1+exp2)
        float h = shh[w][t];
        wsu[U_HJB + i * 32 + t] = f2bf(h);
        float cjn = sj * K1N;
        float sc_, cc_;
        __sincosf(shph[w] * phw[t], &sc_, &cc_);
        // pair (l, l+16) into one uint4 for stage-C pk math
        int p = (t & 15) + 16;                       // partner lane (self for t>=16)
        float h_p  = __shfl(h,   p);
        float c_p  = __shfl(cjn, p);
        float cc_p = __shfl(cc_, p);
        float sc_p = __shfl(sc_, p);
        if (t < 16) {
            uint4 o; o.x = pk2(h, h_p); o.y = pk2(cjn, c_p);
            o.z = pk2(cc_, cc_p); o.w = pk2(sc_, sc_p);
            *(uint4*)(wsu + U_JT + (i * 16 + t) * 8) = o;
        }
    }
}

// ------------- kernel 2: MFMA pairwise core (1 block per i) ---------------
// Diet v2: packed-f32 (v_pk_*) arithmetic around the transcendentals,
// paired reciprocals (rcp count 40->22 per tile per lane), lb-paired JT
// layout for stage C, a_i hoisted to registers (no per-tile LDS reads).
__global__ __launch_bounds__(256, 4) void pair_kernel(
    const float* __restrict__ ws, const unsigned short* __restrict__ wsu,
    float* __restrict__ out) {
    const int i    = blockIdx.x;
    const int tid  = threadIdx.x;
    const int w    = tid >> 6;
    const int lane = tid & 63;
    const int q    = lane >> 4;
    const int m    = lane & 15;
    const int jw   = w * 16;
    const int sub  = lane & 3;

    __shared__ unsigned short W2ls[64 * 72];
    __shared__ unsigned short W3ls[32 * 72];
    __shared__ unsigned short x2ls[4 * 2 * 16 * 72];   // per-wave double buffer
    __shared__ float redT[4][32], redU[4][32], redV[4][32];
    __shared__ float sfw[4];

    // ---- setup ----
    {
        int row = tid >> 2, c = (tid & 3) * 16;
        const uint4* s2 = (const uint4*)(wsu + U_W2B + row * 64 + c);
        uint4 d0 = s2[0], d1 = s2[1];
        uint4* dd = (uint4*)(&W2ls[row * 72 + c]);
        dd[0] = d0; dd[1] = d1;
        if (row < 32) {
            const uint4* s3 = (const uint4*)(wsu + U_W3B + row * 64 + c);
            uint4 e0 = s3[0], e1 = s3[1];
            uint4* d3 = (uint4*)(&W3ls[row * 72 + c]);
            d3[0] = e0; d3[1] = e1;
        }
    }
    v2f hi2[4];                     // own h pairs for fac
    {
        uint4 hv4 = *(const uint4*)(wsu + U_HJB + i * 32 + sub * 8);
        unsigned int hd[4] = {hv4.x, hv4.y, hv4.z, hv4.w};
        #pragma unroll
        for (int e = 0; e < 4; e++) { hi2[e].x = blo(hd[e]); hi2[e].y = bhi(hd[e]); }
    }
    f32x4 b2q[4];              // pre-scaled bias slice for MFMA C-init
    #pragma unroll
    for (int nb = 0; nb < 4; nb++) {
        float4 bv = *(const float4*)(ws + WS_BI2 + nb * 16 + q * 4);
        b2q[nb][0] = bv.x; b2q[nb][1] = bv.y; b2q[nb][2] = bv.z; b2q[nb][3] = bv.w;
    }
    // a_i (pre-scaled) hoisted to registers: loop-invariant across all tiles
    v2f av2[8];
    {
        const float* ap = ws + WS_AA + i * 64 + q * 8;
        #pragma unroll
        for (int s = 0; s < 2; s++) {
            float4 lo = *(const float4*)(ap + s * 32);
            float4 hi = *(const float4*)(ap + s * 32 + 4);
            av2[s * 4 + 0].x = lo.x; av2[s * 4 + 0].y = lo.y;
            av2[s * 4 + 1].x = lo.z; av2[s * 4 + 1].y = lo.w;
            av2[s * 4 + 2].x = hi.x; av2[s * 4 + 2].y = hi.y;
            av2[s * 4 + 3].x = hi.z; av2[s * 4 + 3].y = hi.w;
        }
    }
    v2f hiv2, cib2;            // (l=m, l=m+16) pairs for stage C
    hiv2.x = bf2f(wsu[U_HJB + i * 32 + m]);      hiv2.y = bf2f(wsu[U_HJB + i * 32 + 16 + m]);
    cib2.x = ws[WS_CI + i * 32 + m];             cib2.y = ws[WS_CI + i * 32 + 16 + m];
    const float aggi = ws[WS_AGG + i];
    const float sub0 = (sub == 0) ? 1.0f : 0.0f;

    // ---- streaming pointers + tile-0 prefetch ----
    const unsigned short* hp = wsu + U_HJB + (jw + (lane >> 2)) * 32 + sub * 8;
    const unsigned short* bp = wsu + U_BJB + (jw + m) * 64 + q * 8;
    const unsigned short* jp = wsu + U_JT + ((jw + q * 4) * 16 + m) * 8;

    uint4 hvA = *(const uint4*)hp;
    uint4 b0A = *(const uint4*)bp;
    uint4 b1A = *(const uint4*)(bp + 32);
    uint4 hvB, b0B, b1B;
    __syncthreads();

    // persistent accumulators
    f32x4 accK[2];
    #pragma unroll
    for (int lb = 0; lb < 2; lb++) { accK[lb][0]=0.f; accK[lb][1]=0.f; accK[lb][2]=0.f; accK[lb][3]=0.f; }
    v2f u2; u2.x = 0.f; u2.y = 0.f;
    v2f vv2; vv2.x = 0.f; vv2.y = 0.f;
    float sumfac = 0.f;

    unsigned short* xb0 = &x2ls[w * 2 * 1152];
    unsigned short* xb1 = xb0 + 1152;

    auto stageB = [&](const unsigned short* xb) {
        bf16x8 x2f[2];
        #pragma unroll
        for (int s = 0; s < 2; s++)
            x2f[s] = *(const bf16x8*)(&xb[m * 72 + s * 32 + q * 8]);
        #pragma unroll
        for (int lb = 0; lb < 2; lb++) {
            #pragma unroll
            for (int s = 0; s < 2; s++) {
                bf16x8 w3f = *(const bf16x8*)(&W3ls[(lb * 16 + m) * 72 + s * 32 + q * 8]);
                accK[lb] = __builtin_amdgcn_mfma_f32_16x16x32_bf16(x2f[s], w3f, accK[lb], 0, 0, 0);
            }
        }
    };

    auto body = [&](int T, uint4 hvc, uint4 b0c, uint4 b1c,
                    uint4& hvn, uint4& b0n, uint4& b1n,
                    unsigned short* xcur, const unsigned short* xprev) {
        // prefetch next tile's h/b
        hp += 2048; bp += 4096;
        hvn = *(const uint4*)hp;
        b0n = *(const uint4*)bp;
        b1n = *(const uint4*)(bp + 32);

        // deferred stage B for previous tile (LDS data a full body old)
        if (T > 0) stageB(xprev);

        // 1) fac (lane owns j = T*64 + jw + (lane>>2)); zeroed at j==i
        float facm;
        {
            unsigned int hd[4] = {hvc.x, hvc.y, hvc.z, hvc.w};
            v2f s2v; s2v.x = 0.f; s2v.y = 0.f;
            #pragma unroll
            for (int e = 0; e < 4; e++) {
                v2f hj; hj.x = blo(hd[e]); hj.y = bhi(hd[e]);
                v2f d = hi2[e] - hj;
                s2v += d * d;                      // v_pk_fma
            }
            float s = s2v.x + s2v.y;
            s += __shfl_xor(s, 1); s += __shfl_xor(s, 2);
            int jj = T * 64 + jw + (lane >> 2);
            float facown = fminf(__builtin_amdgcn_rsqf(s), 2.0f) * aggi;
            facown = (jj == i) ? 0.0f : facown;
            sumfac = fmaf(sub0, facown, facown * 0.0f + sumfac);
            facm = __shfl(facown, 4 * m);
        }
        const float fm2 = -2.0f * facm;

        // 2) x1 B-fragments: paired tanh (pk adds, shared rcp)
        bf16x8 afr[2];
        {
            unsigned int bd[8] = {b0c.x, b0c.y, b0c.z, b0c.w, b1c.x, b1c.y, b1c.z, b1c.w};
            #pragma unroll
            for (int s = 0; s < 2; s++) {
                union { uint4 u4; bf16x8 v; } pkd;
                #pragma unroll
                for (int e = 0; e < 4; e++) {
                    unsigned int bw = bd[s * 4 + e];
                    v2f b2; b2.x = blo(bw); b2.y = bhi(bw);
                    v2f t2 = tanh2_pre(av2[s * 4 + e] + b2);
                    ((unsigned int*)&pkd.u4)[e] = pk2(t2.x, t2.y);
                }
                afr[s] = pkd.v;
            }
        }

        // jt loads for CURRENT tile (consumed in stage C; latency hidden
        // under stage A MFMA + epilogue)
        uint4 jt4[4];
        #pragma unroll
        for (int r = 0; r < 4; r++) jt4[r] = *(const uint4*)(jp + r * 128);
        jp += 8192;

        // 3) stage A: X2^T = Wi2' * X1^T, C-init = scaled bias
        f32x4 accA[4];
        #pragma unroll
        for (int nb = 0; nb < 4; nb++) {
            f32x4 acc = b2q[nb];
            #pragma unroll
            for (int s = 0; s < 2; s++) {
                bf16x8 w2f = *(const bf16x8*)(&W2ls[(nb * 16 + m) * 72 + s * 32 + q * 8]);
                acc = __builtin_amdgcn_mfma_f32_16x16x32_bf16(w2f, afr[s], acc, 0, 0, 0);
            }
            accA[nb] = acc;
        }
        // epilogue A: x2s = fma(fm2, rcp(exp2(acc)+1), facm), paired rcp
        #pragma unroll
        for (int nb = 0; nb < 4; nb++) {
            v2f eA; eA.x = __builtin_amdgcn_exp2f(accA[nb][0]); eA.y = __builtin_amdgcn_exp2f(accA[nb][1]);
            v2f eB; eB.x = __builtin_amdgcn_exp2f(accA[nb][2]); eB.y = __builtin_amdgcn_exp2f(accA[nb][3]);
            v2f dA = eA + 1.0f, dB = eB + 1.0f;
            float rA = fast_rcp(dA.x * dA.y), rB = fast_rcp(dB.x * dB.y);
            v2f swA; swA.x = dA.y; swA.y = dA.x;
            v2f swB; swB.x = dB.y; swB.y = dB.x;
            v2f rvA = swA * rA, rvB = swB * rB;      // rcp of each element
            v2f tA = rvA * fm2 + facm;
            v2f tB = rvB * fm2 + facm;
            uint2 pk; pk.x = pk2(tA.x, tA.y); pk.y = pk2(tB.x, tB.y);
            *(uint2*)(&xcur[m * 72 + nb * 16 + q * 4]) = pk;
        }

        // 5) stage C: quantum-term partials, lb-paired (pk math, shared rcp)
        #pragma unroll
        for (int r = 0; r < 4; r++) {
            uint4 jv = jt4[r];
            v2f hj2; hj2.x = blo(jv.x); hj2.y = bhi(jv.x);
            v2f cj2; cj2.x = blo(jv.y); cj2.y = bhi(jv.y);
            v2f pc2; pc2.x = blo(jv.z); pc2.y = bhi(jv.z);
            v2f ps2; ps2.x = blo(jv.w); ps2.y = bhi(jv.w);
            v2f arg = cib2 + cj2;
            v2f ee; ee.x = __builtin_amdgcn_exp2f(arg.x); ee.y = __builtin_amdgcn_exp2f(arg.y);
            v2f dd = ee + 1.0f;
            float rr = fast_rcp(dd.x * dd.y);
            v2f swd; swd.x = dd.y; swd.y = dd.x;
            v2f coh = swd * rr;                    // sigmoid of each element
            v2f cd = coh * (hiv2 - hj2);
            u2  += cd * pc2;
            vv2 += cd * ps2;
        }
    };

    #pragma unroll 1
    for (int T = 0; T < 16; T += 2) {
        body(T,     hvA, b0A, b1A, hvB, b0B, b1B, xb0, xb1);
        body(T + 1, hvB, b0B, b1B, hvA, b0A, b1A, xb1, xb0);
    }
    stageB(xb1);   // tile 15

    // ---- final reductions ----
    float T1[2];
    float aU[2] = {u2.x, u2.y};
    float aV[2] = {vv2.x, vv2.y};
    #pragma unroll
    for (int lb = 0; lb < 2; lb++) {
        T1[lb] = (accK[lb][0] + accK[lb][1]) + (accK[lb][2] + accK[lb][3]);
        T1[lb] += __shfl_xor(T1[lb], 16); T1[lb] += __shfl_xor(T1[lb], 32);
        aU[lb] += __shfl_xor(aU[lb], 16); aU[lb] += __shfl_xor(aU[lb], 32);
        aV[lb] += __shfl_xor(aV[lb], 16); aV[lb] += __shfl_xor(aV[lb], 32);
    }
    sumfac += __shfl_xor(sumfac, 1);  sumfac += __shfl_xor(sumfac, 2);
    sumfac += __shfl_xor(sumfac, 4);  sumfac += __shfl_xor(sumfac, 8);
    sumfac += __shfl_xor(sumfac, 16); sumfac += __shfl_xor(sumfac, 32);
    if (lane < 16) {
        redT[w][m] = T1[0];      redT[w][16 + m] = T1[1];
        redU[w][m] = aU[0];      redU[w][16 + m] = aU[1];
        redV[w][m] = aV[0];      redV[w][16 + m] = aV[1];
    }
    if (lane == 0) sfw[w] = sumfac;
    __syncthreads();
    if (tid < 32) {
        int l = tid;
        float t1 = (redT[0][l] + redT[1][l]) + (redT[2][l] + redT[3][l]);
        float uu = (redU[0][l] + redU[1][l]) + (redU[2][l] + redU[3][l]);
        float vvv = (redV[0][l] + redV[1][l]) + (redV[2][l] + redV[3][l]);
        float sf = (sfw[0] + sfw[1]) + (sfw[2] + sfw[3]);
        int mm = l & 15;
        uint2 jti = *(const uint2*)(wsu + U_JT + (i * 16 + mm) * 8 + 4);  // cc/sc pair words
        float pic = (l < 16) ? blo(jti.x) : bhi(jti.x);
        float pis = (l < 16) ? blo(jti.y) : bhi(jti.y);
        float isum = t1 + sf * ws[WS_BI3 + l] - (pic * uu + pis * vvv);
        out[i * 33 + l] = 0.5f * ws[WS_SELF + i * 32 + l] + 0.3f * isum;
        // parallel |isum| tail reduce (replaces serial tid==0 loop)
        float ab = fabsf(isum);
        ab += __shfl_xor(ab, 1); ab += __shfl_xor(ab, 2);
        ab += __shfl_xor(ab, 4); ab += __shfl_xor(ab, 8);
        ab += __shfl_xor(ab, 16);
        if (tid == 0) out[i * 33 + 32] = 0.1f + 0.05f * ab;
    }
}

extern "C" void kernel_launch(void* const* d_in, const int* in_sizes, int n_in,
                              void* d_out, int out_size, void* d_ws, size_t ws_size,
                              hipStream_t stream) {
    const float* state   = (const float*)d_in[0];
    const float* Ws1     = (const float*)d_in[1];
    const float* bs1     = (const float*)d_in[2];
    const float* Ws2     = (const float*)d_in[3];
    const float* bs2     = (const float*)d_in[4];
    const float* Ws3     = (const float*)d_in[5];
    const float* bs3     = (const float*)d_in[6];
    const float* Wi1     = (const float*)d_in[7];
    const float* bi1     = (const float*)d_in[8];
    const float* Wi2     = (const float*)d_in[9];
    const float* bi2     = (const float*)d_in[10];
    const float* Wi3     = (const float*)d_in[11];
    const float* bi3     = (const float*)d_in[12];
    const float* phase_w = (const float*)d_in[13];
    const float* Wc      = (const float*)d_in[14];
    const float* bc      = (const float*)d_in[15];
    const float* aggr    = (const float*)d_in[16];

    float* ws = (float*)d_ws;
    unsigned short* wsu = (unsigned short*)(ws + WS_FEND);
    float* out = (float*)d_out;

    precompute<<<256, 256, 0, stream>>>(state, Ws1, bs1, Ws2, bs2, Ws3, bs3,
                                        Wi1, bi1, Wi2, bi2, Wi3, bi3,
                                        phase_w, Wc, bc, aggr, ws, wsu);
    pair_kernel<<<NN, 256, 0, stream>>>(ws, wsu, out);
}

// Round 2
// 145.726 us; speedup vs baseline: 1.7099x; 1.7099x over previous
//
#include <hip/hip_runtime.h>
#include <hip/hip_bf16.h>
#include <math.h>

#define NN 1024
#define LDIM 32
#define HDIM 64

// ---------------- fp32 workspace layout (float offsets) ----------------
#define WS_SELF 0                        // N*L   self_term [i][l]
#define WS_AA   (WS_SELF + NN*LDIM)      // N*H   a_i [i][h]  (pre-scaled by 2log2e)
#define WS_CI   (WS_AA   + NN*HDIM)      // N*L   -log2e*(ci+bc) [i][l]
#define WS_AGG  (WS_CI   + NN*LDIM)      // N     sigmoid(aggr)
#define WS_BI2  (WS_AGG  + NN)           // H     bi2 * 2log2e
#define WS_BI3  (WS_BI2  + HDIM)         // L     bi3 (unscaled)
#define WS_FEND (WS_BI3  + LDIM)

// ---------------- bf16(u16) region (short offsets from wsu) -------------
#define U_BJB  0                         // N*H   b_j [j][h]  (pre-scaled by 2log2e)
#define U_HJB  (U_BJB + NN*HDIM)         // N*L   h   [j][l]
#define U_JT   (U_HJB + NN*LDIM)         // N*16*8 paired {h0,h1}{cj0,cj1}{pc0,pc1}{ps0,ps1}
#define U_W2B  (U_JT  + NN*LDIM*4)       // H*H   Wi2 [n][k] * 2log2e
#define U_W3B  (U_W2B + HDIM*HDIM)       // L*H   Wi3 [l][k] (unscaled)
#define U_END  (U_W3B + LDIM*HDIM)

// packed-pair transposed weight tables in precompute LDS (uint offsets)
#define PK_W1  0        // 16*64   Ws1
#define PK_W2  1024     // 32*64   Ws2
#define PK_W3  3072     // 32*32   Ws3
#define PK_WI1 4096     // 64*64   Wi1
#define PK_WC  8192     // 32*32   Wc
#define PK_END 9216     // 36 KB

#define K2P  2.88539008f     // 2*log2(e)
#define K1N  (-1.44269504f)  // -log2(e)

typedef __attribute__((ext_vector_type(8))) short bf16x8;
typedef __attribute__((ext_vector_type(4))) float f32x4;
typedef __attribute__((ext_vector_type(2))) float v2f;

__device__ __forceinline__ float fast_rcp(float x) { return __builtin_amdgcn_rcpf(x); }
__device__ __forceinline__ float fast_tanh(float x) {          // full version (precompute)
    float e = __builtin_amdgcn_exp2f(x * K2P);
    return 1.0f - 2.0f * fast_rcp(e + 1.0f);
}
__device__ __forceinline__ float fast_sigmoid(float x) {       // full version (precompute)
    return fast_rcp(1.0f + __builtin_amdgcn_exp2f(x * K1N));
}
__device__ __forceinline__ float blo(unsigned int u) { union { unsigned int i; float f; } v; v.i = u << 16; return v.f; }
__device__ __forceinline__ float bhi(unsigned int u) { union { unsigned int i; float f; } v; v.i = u & 0xffff0000u; return v.f; }
__device__ __forceinline__ float bf2f(unsigned short u) { union { unsigned int i; float f; } v; v.i = ((unsigned int)u) << 16; return v.f; }
__device__ __forceinline__ unsigned short f2bf(float f) {
    __hip_bfloat16 b = __float2bfloat16(f);
    unsigned short u; __builtin_memcpy(&u, &b, 2); return u;
}
__device__ __forceinline__ unsigned int pk2(float a, float b) {
    float2 t; t.x = a; t.y = b;
    __hip_bfloat162 h = __float22bfloat162_rn(t);
    unsigned int u; __builtin_memcpy(&u, &h, 4); return u;
}

// paired tanh of pre-scaled inputs: one rcp for two lanes of work.
// t_k = 1 - 2*rcp(exp2(xp_k)+1); shared rcp via rr = rcp(d0*d1).
__device__ __forceinline__ v2f tanh2_pre(v2f xp) {
    v2f e; e.x = __builtin_amdgcn_exp2f(xp.x); e.y = __builtin_amdgcn_exp2f(xp.y);
    v2f d = e + 1.0f;
    float rr = fast_rcp(d.x * d.y);
    v2f sw; sw.x = d.y; sw.y = d.x;
    v2f r = sw * rr;                 // r_k = rcp(d_k)
    return 1.0f - 2.0f * r;
}

// ------------- kernel 1: precompute (weights packed in-block) -------------
__global__ __launch_bounds__(256) void precompute(
    const float* __restrict__ state,
    const float* __restrict__ Ws1, const float* __restrict__ bs1,
    const float* __restrict__ Ws2, const float* __restrict__ bs2,
    const float* __restrict__ Ws3, const float* __restrict__ bs3,
    const float* __restrict__ Wi1, const float* __restrict__ bi1,
    const float* __restrict__ Wi2, const float* __restrict__ bi2,
    const float* __restrict__ Wi3, const float* __restrict__ bi3,
    const float* __restrict__ phw, const float* __restrict__ Wc,
    const float* __restrict__ bc,  const float* __restrict__ aggr,
    float* __restrict__ ws, unsigned short* __restrict__ wsu) {
    const int tid = threadIdx.x;
    const int w = tid >> 6, t = tid & 63;
    const int i = blockIdx.x * 4 + w;

    __shared__ unsigned int wlds[PK_END];
    __shared__ float shh[4][32], shdh[4][32], sht1[4][64], sht2[4][64];
    __shared__ float shph[4];

    {
        const float2* s1 = (const float2*)Ws1;
        #pragma unroll
        for (int r = 0; r < 4; r++) { int e = tid + r * 256; int f = e >> 4, k2 = e & 15;
            float2 v = s1[e]; wlds[PK_W1 + k2 * 64 + f] = pk2(v.x, v.y); }
        const float2* s2 = (const float2*)Ws2;
        #pragma unroll
        for (int r = 0; r < 8; r++) { int e = tid + r * 256; int f = e >> 5, k2 = e & 31;
            float2 v = s2[e]; wlds[PK_W2 + k2 * 64 + f] = pk2(v.x, v.y); }
        const float2* s3 = (const float2*)Ws3;
        #pragma unroll
        for (int r = 0; r < 4; r++) { int e = tid + r * 256; int f = e >> 5, k2 = e & 31;
            float2 v = s3[e]; wlds[PK_W3 + k2 * 32 + f] = pk2(v.x, v.y); }
        const float2* si = (const float2*)Wi1;
        #pragma unroll
        for (int r = 0; r < 16; r++) { int e = tid + r * 256; int f = e >> 6, c2 = e & 63;
            float2 v = si[e]; wlds[PK_WI1 + c2 * 64 + f] = pk2(v.x, v.y); }
        const float2* sc = (const float2*)Wc;
        #pragma unroll
        for (int r = 0; r < 4; r++) { int e = tid + r * 256; int f = e >> 5, c2 = e & 31;
            float2 v = sc[e]; wlds[PK_WC + c2 * 32 + f] = pk2(v.x, v.y); }
    }
    if (blockIdx.x == 0) {
        #pragma unroll
        for (int r = 0; r < 16; r++) { int e = tid + r * 256; wsu[U_W2B + e] = f2bf(Wi2[e] * K2P); }
        #pragma unroll
        for (int r = 0; r < 8; r++)  { int e = tid + r * 256; wsu[U_W3B + e] = f2bf(Wi3[e]); }
        if (tid < HDIM) ws[WS_BI2 + tid] = bi2[tid] * K2P;
        if (tid < LDIM) ws[WS_BI3 + tid] = bi3[tid];
    }

    float sv = (t < 33) ? state[i * 33 + t] : 0.f;
    if (t < 32) shh[w][t] = sv;
    if (t == 32) shph[w] = sv;
    if (t == 33) ws[WS_AGG + i] = fast_sigmoid(aggr[i]);
    __syncthreads();

    {
        float s = bs1[t];
        const unsigned int* W = wlds + PK_W1;
        #pragma unroll
        for (int k2 = 0; k2 < 16; k2++) {
            unsigned int p = W[k2 * 64 + t];
            s = fmaf(blo(p), shh[w][2 * k2], s);
            s = fmaf(bhi(p), shh[w][2 * k2 + 1], s);
        }
        sht1[w][t] = fast_tanh(s);
    }
    __syncthreads();
    {
        float s = bs2[t];
        const unsigned int* W = wlds + PK_W2;
        #pragma unroll
        for (int k2 = 0; k2 < 32; k2++) {
            unsigned int p = W[k2 * 64 + t];
            s = fmaf(blo(p), sht1[w][2 * k2], s);
            s = fmaf(bhi(p), sht1[w][2 * k2 + 1], s);
        }
        sht2[w][t] = fast_tanh(s);
    }
    __syncthreads();
    if (t < 32) {
        float s = bs3[t];
        const unsigned int* W = wlds + PK_W3;
        #pragma unroll
        for (int k2 = 0; k2 < 32; k2++) {
            unsigned int p = W[k2 * 32 + t];
            s = fmaf(blo(p), sht2[w][2 * k2], s);
            s = fmaf(bhi(p), sht2[w][2 * k2 + 1], s);
        }
        ws[WS_SELF + i * 32 + t] = s;
        shdh[w][t] = s;
    }
    __syncthreads();
    {
        float sa = 0.f, sb = bi1[t];
        const unsigned int* W = wlds + PK_WI1;
        #pragma unroll
        for (int k2 = 0; k2 < 16; k2++) {
            float h0 = shh[w][2 * k2], h1 = shh[w][2 * k2 + 1];
            float d0 = shdh[w][2 * k2], d1 = shdh[w][2 * k2 + 1];
            unsigned int wa  = W[k2 * 64 + t];
            unsigned int wb  = W[(16 + k2) * 64 + t];
            unsigned int wa2 = W[(32 + k2) * 64 + t];
            unsigned int wb2 = W[(48 + k2) * 64 + t];
            sa = fmaf(blo(wa), h0, sa);  sa = fmaf(bhi(wa), h1, sa);
            sb = fmaf(blo(wb), h0, sb);  sb = fmaf(bhi(wb), h1, sb);
            sa = fmaf(blo(wa2), d0, sa); sa = fmaf(bhi(wa2), d1, sa);
            sb = fmaf(blo(wb2), d0, sb); sb = fmaf(bhi(wb2), d1, sb);
        }
        ws[WS_AA + i * 64 + t]  = sa * K2P;          // pre-scaled for tanh_pre
        wsu[U_BJB + i * 64 + t] = f2bf(sb * K2P);
    }
    if (t < 32) {
        float si2 = 0.f, sj = 0.f;
        const unsigned int* W = wlds + PK_WC;
        #pragma unroll
        for (int m2 = 0; m2 < 16; m2++) {
            float h0 = shh[w][2 * m2], h1 = shh[w][2 * m2 + 1];
            unsigned int wi = W[m2 * 32 + t];
            unsigned int wj = W[(16 + m2) * 32 + t];
            si2 = fmaf(blo(wi), h0, si2); si2 = fmaf(bhi(wi), h1, si2);
            sj  = fmaf(blo(wj), h0, sj);  sj  = fmaf(bhi(wj), h1, sj);
        }
        ws[WS_CI + i * 32 + t] = (si2 + bc[t]) * K1N; // pre-scaled for rcp(1+exp2)
        float h = shh[w][t];
        wsu[U_HJB + i * 32 + t] = f2bf(h);
        float cjn = sj * K1N;
        float sc_, cc_;
        __sincosf(shph[w] * phw[t], &sc_, &cc_);
        // pair (l, l+16) into one uint4 for stage-C pk math
        int p = (t & 15) + 16;                       // partner lane (self for t>=16)
        float h_p  = __shfl(h,   p);
        float c_p  = __shfl(cjn, p);
        float cc_p = __shfl(cc_, p);
        float sc_p = __shfl(sc_, p);
        if (t < 16) {
            uint4 o; o.x = pk2(h, h_p); o.y = pk2(cjn, c_p);
            o.z = pk2(cc_, cc_p); o.w = pk2(sc_, sc_p);
            *(uint4*)(wsu + U_JT + (i * 16 + t) * 8) = o;
        }
    }
}

// ------------- kernel 2: MFMA pairwise core (1 block per i) ---------------
// Diet v2 (fixed): packed-f32 arithmetic around the transcendentals, paired
// reciprocals, lb-paired JT layout, a_i hoisted to registers. NO occupancy
// pin: __launch_bounds__(256,4) forced VGPR=64 and spilled the whole
// working set to scratch (FETCH_SIZE 2.2MB -> 352MB, 66 -> 168us). The
// allocator needs ~125 VGPRs; both 108 and 125 sit in the same 4-waves/SIMD
// occupancy tier, so an unpinned build loses nothing.
__global__ __launch_bounds__(256) void pair_kernel(
    const float* __restrict__ ws, const unsigned short* __restrict__ wsu,
    float* __restrict__ out) {
    const int i    = blockIdx.x;
    const int tid  = threadIdx.x;
    const int w    = tid >> 6;
    const int lane = tid & 63;
    const int q    = lane >> 4;
    const int m    = lane & 15;
    const int jw   = w * 16;
    const int sub  = lane & 3;

    __shared__ unsigned short W2ls[64 * 72];
    __shared__ unsigned short W3ls[32 * 72];
    __shared__ unsigned short x2ls[4 * 2 * 16 * 72];   // per-wave double buffer
    __shared__ float redT[4][32], redU[4][32], redV[4][32];
    __shared__ float sfw[4];

    // ---- setup ----
    {
        int row = tid >> 2, c = (tid & 3) * 16;
        const uint4* s2 = (const uint4*)(wsu + U_W2B + row * 64 + c);
        uint4 d0 = s2[0], d1 = s2[1];
        uint4* dd = (uint4*)(&W2ls[row * 72 + c]);
        dd[0] = d0; dd[1] = d1;
        if (row < 32) {
            const uint4* s3 = (const uint4*)(wsu + U_W3B + row * 64 + c);
            uint4 e0 = s3[0], e1 = s3[1];
            uint4* d3 = (uint4*)(&W3ls[row * 72 + c]);
            d3[0] = e0; d3[1] = e1;
        }
    }
    v2f hi2[4];                     // own h pairs for fac
    {
        uint4 hv4 = *(const uint4*)(wsu + U_HJB + i * 32 + sub * 8);
        unsigned int hd[4] = {hv4.x, hv4.y, hv4.z, hv4.w};
        #pragma unroll
        for (int e = 0; e < 4; e++) { hi2[e].x = blo(hd[e]); hi2[e].y = bhi(hd[e]); }
    }
    f32x4 b2q[4];              // pre-scaled bias slice for MFMA C-init
    #pragma unroll
    for (int nb = 0; nb < 4; nb++) {
        float4 bv = *(const float4*)(ws + WS_BI2 + nb * 16 + q * 4);
        b2q[nb][0] = bv.x; b2q[nb][1] = bv.y; b2q[nb][2] = bv.z; b2q[nb][3] = bv.w;
    }
    // a_i (pre-scaled) hoisted to registers: loop-invariant across all tiles
    v2f av2[8];
    {
        const float* ap = ws + WS_AA + i * 64 + q * 8;
        #pragma unroll
        for (int s = 0; s < 2; s++) {
            float4 lo = *(const float4*)(ap + s * 32);
            float4 hi = *(const float4*)(ap + s * 32 + 4);
            av2[s * 4 + 0].x = lo.x; av2[s * 4 + 0].y = lo.y;
            av2[s * 4 + 1].x = lo.z; av2[s * 4 + 1].y = lo.w;
            av2[s * 4 + 2].x = hi.x; av2[s * 4 + 2].y = hi.y;
            av2[s * 4 + 3].x = hi.z; av2[s * 4 + 3].y = hi.w;
        }
    }
    v2f hiv2, cib2;            // (l=m, l=m+16) pairs for stage C
    hiv2.x = bf2f(wsu[U_HJB + i * 32 + m]);      hiv2.y = bf2f(wsu[U_HJB + i * 32 + 16 + m]);
    cib2.x = ws[WS_CI + i * 32 + m];             cib2.y = ws[WS_CI + i * 32 + 16 + m];
    const float aggi = ws[WS_AGG + i];
    const float sub0 = (sub == 0) ? 1.0f : 0.0f;

    // ---- streaming pointers + tile-0 prefetch ----
    const unsigned short* hp = wsu + U_HJB + (jw + (lane >> 2)) * 32 + sub * 8;
    const unsigned short* bp = wsu + U_BJB + (jw + m) * 64 + q * 8;
    const unsigned short* jp = wsu + U_JT + ((jw + q * 4) * 16 + m) * 8;

    uint4 hvA = *(const uint4*)hp;
    uint4 b0A = *(const uint4*)bp;
    uint4 b1A = *(const uint4*)(bp + 32);
    uint4 hvB, b0B, b1B;
    __syncthreads();

    // persistent accumulators
    f32x4 accK[2];
    #pragma unroll
    for (int lb = 0; lb < 2; lb++) { accK[lb][0]=0.f; accK[lb][1]=0.f; accK[lb][2]=0.f; accK[lb][3]=0.f; }
    v2f u2; u2.x = 0.f; u2.y = 0.f;
    v2f vv2; vv2.x = 0.f; vv2.y = 0.f;
    float sumfac = 0.f;

    unsigned short* xb0 = &x2ls[w * 2 * 1152];
    unsigned short* xb1 = xb0 + 1152;

    auto stageB = [&](const unsigned short* xb) {
        bf16x8 x2f[2];
        #pragma unroll
        for (int s = 0; s < 2; s++)
            x2f[s] = *(const bf16x8*)(&xb[m * 72 + s * 32 + q * 8]);
        #pragma unroll
        for (int lb = 0; lb < 2; lb++) {
            #pragma unroll
            for (int s = 0; s < 2; s++) {
                bf16x8 w3f = *(const bf16x8*)(&W3ls[(lb * 16 + m) * 72 + s * 32 + q * 8]);
                accK[lb] = __builtin_amdgcn_mfma_f32_16x16x32_bf16(x2f[s], w3f, accK[lb], 0, 0, 0);
            }
        }
    };

    auto body = [&](int T, uint4 hvc, uint4 b0c, uint4 b1c,
                    uint4& hvn, uint4& b0n, uint4& b1n,
                    unsigned short* xcur, const unsigned short* xprev) {
        // prefetch next tile's h/b
        hp += 2048; bp += 4096;
        hvn = *(const uint4*)hp;
        b0n = *(const uint4*)bp;
        b1n = *(const uint4*)(bp + 32);

        // deferred stage B for previous tile (LDS data a full body old)
        if (T > 0) stageB(xprev);

        // 1) fac (lane owns j = T*64 + jw + (lane>>2)); zeroed at j==i
        float facm;
        {
            unsigned int hd[4] = {hvc.x, hvc.y, hvc.z, hvc.w};
            v2f s2v; s2v.x = 0.f; s2v.y = 0.f;
            #pragma unroll
            for (int e = 0; e < 4; e++) {
                v2f hj; hj.x = blo(hd[e]); hj.y = bhi(hd[e]);
                v2f d = hi2[e] - hj;
                s2v += d * d;                      // v_pk_fma
            }
            float s = s2v.x + s2v.y;
            s += __shfl_xor(s, 1); s += __shfl_xor(s, 2);
            int jj = T * 64 + jw + (lane >> 2);
            float facown = fminf(__builtin_amdgcn_rsqf(s), 2.0f) * aggi;
            facown = (jj == i) ? 0.0f : facown;
            sumfac = fmaf(sub0, facown, sumfac);
            facm = __shfl(facown, 4 * m);
        }
        const float fm2 = -2.0f * facm;

        // 2) x1 B-fragments: paired tanh (pk adds, shared rcp)
        bf16x8 afr[2];
        {
            unsigned int bd[8] = {b0c.x, b0c.y, b0c.z, b0c.w, b1c.x, b1c.y, b1c.z, b1c.w};
            #pragma unroll
            for (int s = 0; s < 2; s++) {
                union { uint4 u4; bf16x8 v; } pkd;
                #pragma unroll
                for (int e = 0; e < 4; e++) {
                    unsigned int bw = bd[s * 4 + e];
                    v2f b2; b2.x = blo(bw); b2.y = bhi(bw);
                    v2f t2 = tanh2_pre(av2[s * 4 + e] + b2);
                    ((unsigned int*)&pkd.u4)[e] = pk2(t2.x, t2.y);
                }
                afr[s] = pkd.v;
            }
        }

        // jt loads for CURRENT tile (consumed in stage C; latency hidden
        // under stage A MFMA + epilogue)
        uint4 jt4[4];
        #pragma unroll
        for (int r = 0; r < 4; r++) jt4[r] = *(const uint4*)(jp + r * 128);
        jp += 8192;

        // 3) stage A: X2^T = Wi2' * X1^T, C-init = scaled bias
        f32x4 accA[4];
        #pragma unroll
        for (int nb = 0; nb < 4; nb++) {
            f32x4 acc = b2q[nb];
            #pragma unroll
            for (int s = 0; s < 2; s++) {
                bf16x8 w2f = *(const bf16x8*)(&W2ls[(nb * 16 + m) * 72 + s * 32 + q * 8]);
                acc = __builtin_amdgcn_mfma_f32_16x16x32_bf16(w2f, afr[s], acc, 0, 0, 0);
            }
            accA[nb] = acc;
        }
        // epilogue A: x2s = fma(fm2, rcp(exp2(acc)+1), facm), paired rcp
        #pragma unroll
        for (int nb = 0; nb < 4; nb++) {
            v2f eA; eA.x = __builtin_amdgcn_exp2f(accA[nb][0]); eA.y = __builtin_amdgcn_exp2f(accA[nb][1]);
            v2f eB; eB.x = __builtin_amdgcn_exp2f(accA[nb][2]); eB.y = __builtin_amdgcn_exp2f(accA[nb][3]);
            v2f dA = eA + 1.0f, dB = eB + 1.0f;
            float rA = fast_rcp(dA.x * dA.y), rB = fast_rcp(dB.x * dB.y);
            v2f swA; swA.x = dA.y; swA.y = dA.x;
            v2f swB; swB.x = dB.y; swB.y = dB.x;
            v2f rvA = swA * rA, rvB = swB * rB;      // rcp of each element
            v2f tA = rvA * fm2 + facm;
            v2f tB = rvB * fm2 + facm;
            uint2 pk; pk.x = pk2(tA.x, tA.y); pk.y = pk2(tB.x, tB.y);
            *(uint2*)(&xcur[m * 72 + nb * 16 + q * 4]) = pk;
        }

        // 5) stage C: quantum-term partials, lb-paired (pk math, shared rcp)
        #pragma unroll
        for (int r = 0; r < 4; r++) {
            uint4 jv = jt4[r];
            v2f hj2; hj2.x = blo(jv.x); hj2.y = bhi(jv.x);
            v2f cj2; cj2.x = blo(jv.y); cj2.y = bhi(jv.y);
            v2f pc2; pc2.x = blo(jv.z); pc2.y = bhi(jv.z);
            v2f ps2; ps2.x = blo(jv.w); ps2.y = bhi(jv.w);
            v2f arg = cib2 + cj2;
            v2f ee; ee.x = __builtin_amdgcn_exp2f(arg.x); ee.y = __builtin_amdgcn_exp2f(arg.y);
            v2f dd = ee + 1.0f;
            float rr = fast_rcp(dd.x * dd.y);
            v2f swd; swd.x = dd.y; swd.y = dd.x;
            v2f coh = swd * rr;                    // sigmoid of each element
            v2f cd = coh * (hiv2 - hj2);
            u2  += cd * pc2;
            vv2 += cd * ps2;
        }
    };

    #pragma unroll 1
    for (int T = 0; T < 16; T += 2) {
        body(T,     hvA, b0A, b1A, hvB, b0B, b1B, xb0, xb1);
        body(T + 1, hvB, b0B, b1B, hvA, b0A, b1A, xb1, xb0);
    }
    stageB(xb1);   // tile 15

    // ---- final reductions ----
    float T1[2];
    float aU[2] = {u2.x, u2.y};
    float aV[2] = {vv2.x, vv2.y};
    #pragma unroll
    for (int lb = 0; lb < 2; lb++) {
        T1[lb] = (accK[lb][0] + accK[lb][1]) + (accK[lb][2] + accK[lb][3]);
        T1[lb] += __shfl_xor(T1[lb], 16); T1[lb] += __shfl_xor(T1[lb], 32);
        aU[lb] += __shfl_xor(aU[lb], 16); aU[lb] += __shfl_xor(aU[lb], 32);
        aV[lb] += __shfl_xor(aV[lb], 16); aV[lb] += __shfl_xor(aV[lb], 32);
    }
    sumfac += __shfl_xor(sumfac, 1);  sumfac += __shfl_xor(sumfac, 2);
    sumfac += __shfl_xor(sumfac, 4);  sumfac += __shfl_xor(sumfac, 8);
    sumfac += __shfl_xor(sumfac, 16); sumfac += __shfl_xor(sumfac, 32);
    if (lane < 16) {
        redT[w][m] = T1[0];      redT[w][16 + m] = T1[1];
        redU[w][m] = aU[0];      redU[w][16 + m] = aU[1];
        redV[w][m] = aV[0];      redV[w][16 + m] = aV[1];
    }
    if (lane == 0) sfw[w] = sumfac;
    __syncthreads();
    if (tid < 32) {
        int l = tid;
        float t1 = (redT[0][l] + redT[1][l]) + (redT[2][l] + redT[3][l]);
        float uu = (redU[0][l] + redU[1][l]) + (redU[2][l] + redU[3][l]);
        float vvv = (redV[0][l] + redV[1][l]) + (redV[2][l] + redV[3][l]);
        float sf = (sfw[0] + sfw[1]) + (sfw[2] + sfw[3]);
        int mm = l & 15;
        uint2 jti = *(const uint2*)(wsu + U_JT + (i * 16 + mm) * 8 + 4);  // cc/sc pair words
        float pic = (l < 16) ? blo(jti.x) : bhi(jti.x);
        float pis = (l < 16) ? blo(jti.y) : bhi(jti.y);
        float isum = t1 + sf * ws[WS_BI3 + l] - (pic * uu + pis * vvv);
        out[i * 33 + l] = 0.5f * ws[WS_SELF + i * 32 + l] + 0.3f * isum;
        // parallel |isum| tail reduce (replaces serial tid==0 loop)
        float ab = fabsf(isum);
        ab += __shfl_xor(ab, 1); ab += __shfl_xor(ab, 2);
        ab += __shfl_xor(ab, 4); ab += __shfl_xor(ab, 8);
        ab += __shfl_xor(ab, 16);
        if (tid == 0) out[i * 33 + 32] = 0.1f + 0.05f * ab;
    }
}

extern "C" void kernel_launch(void* const* d_in, const int* in_sizes, int n_in,
                              void* d_out, int out_size, void* d_ws, size_t ws_size,
                              hipStream_t stream) {
    const float* state   = (const float*)d_in[0];
    const float* Ws1     = (const float*)d_in[1];
    const float* bs1     = (const float*)d_in[2];
    const float* Ws2     = (const float*)d_in[3];
    const float* bs2     = (const float*)d_in[4];
    const float* Ws3     = (const float*)d_in[5];
    const float* bs3     = (const float*)d_in[6];
    const float* Wi1     = (const float*)d_in[7];
    const float* bi1     = (const float*)d_in[8];
    const float* Wi2     = (const float*)d_in[9];
    const float* bi2     = (const float*)d_in[10];
    const float* Wi3     = (const float*)d_in[11];
    const float* bi3     = (const float*)d_in[12];
    const float* phase_w = (const float*)d_in[13];
    const float* Wc      = (const float*)d_in[14];
    const float* bc      = (const float*)d_in[15];
    const float* aggr    = (const float*)d_in[16];

    float* ws = (float*)d_ws;
    unsigned short* wsu = (unsigned short*)(ws + WS_FEND);
    float* out = (float*)d_out;

    precompute<<<256, 256, 0, stream>>>(state, Ws1, bs1, Ws2, bs2, Ws3, bs3,
                                        Wi1, bi1, Wi2, bi2, Wi3, bi3,
                                        phase_w, Wc, bc, aggr, ws, wsu);
    pair_kernel<<<NN, 256, 0, stream>>>(ws, wsu, out);
}

// Round 3
// 143.390 us; speedup vs baseline: 1.7378x; 1.0163x over previous
//
#include <hip/hip_runtime.h>
#include <hip/hip_bf16.h>
#include <math.h>

#define NN 1024
#define LDIM 32
#define HDIM 64

// ---------------- fp32 workspace layout (float offsets) ----------------
#define WS_SELF 0                        // N*L   self_term [i][l]
#define WS_AA   (WS_SELF + NN*LDIM)      // N*H   Ea = 2^(2log2e * a_i) [i][h]
#define WS_CI   (WS_AA   + NN*HDIM)      // N*L   Ei = 2^(-log2e*(ci+bc)) [i][l]
#define WS_AGG  (WS_CI   + NN*LDIM)      // N     sigmoid(aggr)
#define WS_BI2  (WS_AGG  + NN)           // H     bi2 * 2log2e
#define WS_BI3  (WS_BI2  + HDIM)         // L     bi3 (unscaled)
#define WS_FEND (WS_BI3  + LDIM)

// ---------------- bf16(u16) region (short offsets from wsu) -------------
#define U_BJB  0                         // N*H   Eb = 2^(2log2e * b_j) [j][h]
#define U_HJB  (U_BJB + NN*HDIM)         // N*L   h   [j][l]
#define U_JT   (U_HJB + NN*LDIM)         // N*16*8 paired {h0,h1}{Ej0,Ej1}{pc0,pc1}{ps0,ps1}
#define U_W2B  (U_JT  + NN*LDIM*4)       // H*H   Wi2 [n][k] * 2log2e
#define U_W3B  (U_W2B + HDIM*HDIM)       // L*H   Wi3 [l][k] (unscaled)
#define U_END  (U_W3B + LDIM*HDIM)

// packed-pair transposed weight tables in precompute LDS (uint offsets)
#define PK_W1  0        // 16*64   Ws1
#define PK_W2  1024     // 32*64   Ws2
#define PK_W3  3072     // 32*32   Ws3
#define PK_WI1 4096     // 64*64   Wi1
#define PK_WC  8192     // 32*32   Wc
#define PK_END 9216     // 36 KB

#define K2P  2.88539008f     // 2*log2(e)
#define K1N  (-1.44269504f)  // -log2(e)

typedef __attribute__((ext_vector_type(8))) short bf16x8;
typedef __attribute__((ext_vector_type(4))) float f32x4;
typedef __attribute__((ext_vector_type(2))) float v2f;

__device__ __forceinline__ float fast_rcp(float x) { return __builtin_amdgcn_rcpf(x); }
__device__ __forceinline__ float fast_tanh(float x) {          // full version (precompute)
    float e = __builtin_amdgcn_exp2f(x * K2P);
    return 1.0f - 2.0f * fast_rcp(e + 1.0f);
}
__device__ __forceinline__ float fast_sigmoid(float x) {       // full version (precompute)
    return fast_rcp(1.0f + __builtin_amdgcn_exp2f(x * K1N));
}
__device__ __forceinline__ float blo(unsigned int u) { union { unsigned int i; float f; } v; v.i = u << 16; return v.f; }
__device__ __forceinline__ float bhi(unsigned int u) { union { unsigned int i; float f; } v; v.i = u & 0xffff0000u; return v.f; }
__device__ __forceinline__ float bf2f(unsigned short u) { union { unsigned int i; float f; } v; v.i = ((unsigned int)u) << 16; return v.f; }
__device__ __forceinline__ unsigned short f2bf(float f) {
    __hip_bfloat16 b = __float2bfloat16(f);
    unsigned short u; __builtin_memcpy(&u, &b, 2); return u;
}
__device__ __forceinline__ unsigned int pk2(float a, float b) {
    float2 t; t.x = a; t.y = b;
    __hip_bfloat162 h = __float22bfloat162_rn(t);
    unsigned int u; __builtin_memcpy(&u, &h, 4); return u;
}

// factored paired tanh: tanh of pre-scaled (p_i + q_j) where Ea = 2^p (f32
// reg, loop-invariant) and Eb = 2^q (streamed bf16). d = Ea*Eb + 1 is one
// pk-fma -- no exp2 in the inner loop. Shared rcp for the pair.
__device__ __forceinline__ v2f tanh2_fact(v2f ea, v2f eb) {
    v2f d = ea * eb + 1.0f;
    float rr = fast_rcp(d.x * d.y);
    v2f sw; sw.x = d.y; sw.y = d.x;
    v2f r = sw * rr;                 // r_k = rcp(d_k)
    return 1.0f - 2.0f * r;
}

// ------------- kernel 1: precompute (weights packed in-block) -------------
__global__ __launch_bounds__(256) void precompute(
    const float* __restrict__ state,
    const float* __restrict__ Ws1, const float* __restrict__ bs1,
    const float* __restrict__ Ws2, const float* __restrict__ bs2,
    const float* __restrict__ Ws3, const float* __restrict__ bs3,
    const float* __restrict__ Wi1, const float* __restrict__ bi1,
    const float* __restrict__ Wi2, const float* __restrict__ bi2,
    const float* __restrict__ Wi3, const float* __restrict__ bi3,
    const float* __restrict__ phw, const float* __restrict__ Wc,
    const float* __restrict__ bc,  const float* __restrict__ aggr,
    float* __restrict__ ws, unsigned short* __restrict__ wsu) {
    const int tid = threadIdx.x;
    const int w = tid >> 6, t = tid & 63;
    const int i = blockIdx.x * 4 + w;

    __shared__ unsigned int wlds[PK_END];
    __shared__ float shh[4][32], shdh[4][32], sht1[4][64], sht2[4][64];
    __shared__ float shph[4];

    {
        const float2* s1 = (const float2*)Ws1;
        #pragma unroll
        for (int r = 0; r < 4; r++) { int e = tid + r * 256; int f = e >> 4, k2 = e & 15;
            float2 v = s1[e]; wlds[PK_W1 + k2 * 64 + f] = pk2(v.x, v.y); }
        const float2* s2 = (const float2*)Ws2;
        #pragma unroll
        for (int r = 0; r < 8; r++) { int e = tid + r * 256; int f = e >> 5, k2 = e & 31;
            float2 v = s2[e]; wlds[PK_W2 + k2 * 64 + f] = pk2(v.x, v.y); }
        const float2* s3 = (const float2*)Ws3;
        #pragma unroll
        for (int r = 0; r < 4; r++) { int e = tid + r * 256; int f = e >> 5, k2 = e & 31;
            float2 v = s3[e]; wlds[PK_W3 + k2 * 32 + f] = pk2(v.x, v.y); }
        const float2* si = (const float2*)Wi1;
        #pragma unroll
        for (int r = 0; r < 16; r++) { int e = tid + r * 256; int f = e >> 6, c2 = e & 63;
            float2 v = si[e]; wlds[PK_WI1 + c2 * 64 + f] = pk2(v.x, v.y); }
        const float2* sc = (const float2*)Wc;
        #pragma unroll
        for (int r = 0; r < 4; r++) { int e = tid + r * 256; int f = e >> 5, c2 = e & 31;
            float2 v = sc[e]; wlds[PK_WC + c2 * 32 + f] = pk2(v.x, v.y); }
    }
    if (blockIdx.x == 0) {
        #pragma unroll
        for (int r = 0; r < 16; r++) { int e = tid + r * 256; wsu[U_W2B + e] = f2bf(Wi2[e] * K2P); }
        #pragma unroll
        for (int r = 0; r < 8; r++)  { int e = tid + r * 256; wsu[U_W3B + e] = f2bf(Wi3[e]); }
        if (tid < HDIM) ws[WS_BI2 + tid] = bi2[tid] * K2P;
        if (tid < LDIM) ws[WS_BI3 + tid] = bi3[tid];
    }

    float sv = (t < 33) ? state[i * 33 + t] : 0.f;
    if (t < 32) shh[w][t] = sv;
    if (t == 32) shph[w] = sv;
    if (t == 33) ws[WS_AGG + i] = fast_sigmoid(aggr[i]);
    __syncthreads();

    {
        float s = bs1[t];
        const unsigned int* W = wlds + PK_W1;
        #pragma unroll
        for (int k2 = 0; k2 < 16; k2++) {
            unsigned int p = W[k2 * 64 + t];
            s = fmaf(blo(p), shh[w][2 * k2], s);
            s = fmaf(bhi(p), shh[w][2 * k2 + 1], s);
        }
        sht1[w][t] = fast_tanh(s);
    }
    __syncthreads();
    {
        float s = bs2[t];
        const unsigned int* W = wlds + PK_W2;
        #pragma unroll
        for (int k2 = 0; k2 < 32; k2++) {
            unsigned int p = W[k2 * 64 + t];
            s = fmaf(blo(p), sht1[w][2 * k2], s);
            s = fmaf(bhi(p), sht1[w][2 * k2 + 1], s);
        }
        sht2[w][t] = fast_tanh(s);
    }
    __syncthreads();
    if (t < 32) {
        float s = bs3[t];
        const unsigned int* W = wlds + PK_W3;
        #pragma unroll
        for (int k2 = 0; k2 < 32; k2++) {
            unsigned int p = W[k2 * 32 + t];
            s = fmaf(blo(p), sht2[w][2 * k2], s);
            s = fmaf(bhi(p), sht2[w][2 * k2 + 1], s);
        }
        ws[WS_SELF + i * 32 + t] = s;
        shdh[w][t] = s;
    }
    __syncthreads();
    {
        float sa = 0.f, sb = bi1[t];
        const unsigned int* W = wlds + PK_WI1;
        #pragma unroll
        for (int k2 = 0; k2 < 16; k2++) {
            float h0 = shh[w][2 * k2], h1 = shh[w][2 * k2 + 1];
            float d0 = shdh[w][2 * k2], d1 = shdh[w][2 * k2 + 1];
            unsigned int wa  = W[k2 * 64 + t];
            unsigned int wb  = W[(16 + k2) * 64 + t];
            unsigned int wa2 = W[(32 + k2) * 64 + t];
            unsigned int wb2 = W[(48 + k2) * 64 + t];
            sa = fmaf(blo(wa), h0, sa);  sa = fmaf(bhi(wa), h1, sa);
            sb = fmaf(blo(wb), h0, sb);  sb = fmaf(bhi(wb), h1, sb);
            sa = fmaf(blo(wa2), d0, sa); sa = fmaf(bhi(wa2), d1, sa);
            sb = fmaf(blo(wb2), d0, sb); sb = fmaf(bhi(wb2), d1, sb);
        }
        // exp-factorized: store E = 2^(pre-scaled logit) instead of logit
        ws[WS_AA + i * 64 + t]  = __builtin_amdgcn_exp2f(sa * K2P);
        wsu[U_BJB + i * 64 + t] = f2bf(__builtin_amdgcn_exp2f(sb * K2P));
    }
    if (t < 32) {
        float si2 = 0.f, sj = 0.f;
        const unsigned int* W = wlds + PK_WC;
        #pragma unroll
        for (int m2 = 0; m2 < 16; m2++) {
            float h0 = shh[w][2 * m2], h1 = shh[w][2 * m2 + 1];
            unsigned int wi = W[m2 * 32 + t];
            unsigned int wj = W[(16 + m2) * 32 + t];
            si2 = fmaf(blo(wi), h0, si2); si2 = fmaf(bhi(wi), h1, si2);
            sj  = fmaf(blo(wj), h0, sj);  sj  = fmaf(bhi(wj), h1, sj);
        }
        // Ei = 2^(-log2e*(ci+bc)); sigmoid(ci+cj) = rcp(1 + Ei*Ej)
        ws[WS_CI + i * 32 + t] = __builtin_amdgcn_exp2f((si2 + bc[t]) * K1N);
        float h = shh[w][t];
        wsu[U_HJB + i * 32 + t] = f2bf(h);
        float ejn = __builtin_amdgcn_exp2f(sj * K1N);
        float sc_, cc_;
        __sincosf(shph[w] * phw[t], &sc_, &cc_);
        // pair (l, l+16) into one uint4 for stage-C pk math
        int p = (t & 15) + 16;                       // partner lane (self for t>=16)
        float h_p  = __shfl(h,   p);
        float e_p  = __shfl(ejn, p);
        float cc_p = __shfl(cc_, p);
        float sc_p = __shfl(sc_, p);
        if (t < 16) {
            uint4 o; o.x = pk2(h, h_p); o.y = pk2(ejn, e_p);
            o.z = pk2(cc_, cc_p); o.w = pk2(sc_, sc_p);
            *(uint4*)(wsu + U_JT + (i * 16 + t) * 8) = o;
        }
    }
}

// ------------- kernel 2: MFMA pairwise core (1 block per i) ---------------
// Diet v3: exponential factorization. 2^(p_i+q_j) = Ea*Eb with Ea in
// registers (loop-invariant) and Eb/Ej streamed -- removes 24 of 40 exp2
// per tile per lane from the inner loop (exp2 is quarter-rate); only the
// epilogue sigmoid (MFMA output) still needs exp2. Occupancy note: grid is
// exactly 4 blocks/CU (1024 blocks), so waves/CU is grid-limited at 16 --
// LDS/VGPR trims below the current tier buy nothing.
__global__ __launch_bounds__(256) void pair_kernel(
    const float* __restrict__ ws, const unsigned short* __restrict__ wsu,
    float* __restrict__ out) {
    const int i    = blockIdx.x;
    const int tid  = threadIdx.x;
    const int w    = tid >> 6;
    const int lane = tid & 63;
    const int q    = lane >> 4;
    const int m    = lane & 15;
    const int jw   = w * 16;
    const int sub  = lane & 3;

    __shared__ unsigned short W2ls[64 * 72];
    __shared__ unsigned short W3ls[32 * 72];
    __shared__ unsigned short x2ls[4 * 2 * 16 * 72];   // per-wave double buffer
    __shared__ float redT[4][32], redU[4][32], redV[4][32];
    __shared__ float sfw[4];

    // ---- setup ----
    {
        int row = tid >> 2, c = (tid & 3) * 16;
        const uint4* s2 = (const uint4*)(wsu + U_W2B + row * 64 + c);
        uint4 d0 = s2[0], d1 = s2[1];
        uint4* dd = (uint4*)(&W2ls[row * 72 + c]);
        dd[0] = d0; dd[1] = d1;
        if (row < 32) {
            const uint4* s3 = (const uint4*)(wsu + U_W3B + row * 64 + c);
            uint4 e0 = s3[0], e1 = s3[1];
            uint4* d3 = (uint4*)(&W3ls[row * 72 + c]);
            d3[0] = e0; d3[1] = e1;
        }
    }
    v2f hi2[4];                     // own h pairs for fac
    {
        uint4 hv4 = *(const uint4*)(wsu + U_HJB + i * 32 + sub * 8);
        unsigned int hd[4] = {hv4.x, hv4.y, hv4.z, hv4.w};
        #pragma unroll
        for (int e = 0; e < 4; e++) { hi2[e].x = blo(hd[e]); hi2[e].y = bhi(hd[e]); }
    }
    f32x4 b2q[4];              // pre-scaled bias slice for MFMA C-init
    #pragma unroll
    for (int nb = 0; nb < 4; nb++) {
        float4 bv = *(const float4*)(ws + WS_BI2 + nb * 16 + q * 4);
        b2q[nb][0] = bv.x; b2q[nb][1] = bv.y; b2q[nb][2] = bv.z; b2q[nb][3] = bv.w;
    }
    // Ea = 2^(pre-scaled a_i): loop-invariant across all tiles, in registers
    v2f ea2[8];
    {
        const float* ap = ws + WS_AA + i * 64 + q * 8;
        #pragma unroll
        for (int s = 0; s < 2; s++) {
            float4 lo = *(const float4*)(ap + s * 32);
            float4 hi = *(const float4*)(ap + s * 32 + 4);
            ea2[s * 4 + 0].x = lo.x; ea2[s * 4 + 0].y = lo.y;
            ea2[s * 4 + 1].x = lo.z; ea2[s * 4 + 1].y = lo.w;
            ea2[s * 4 + 2].x = hi.x; ea2[s * 4 + 2].y = hi.y;
            ea2[s * 4 + 3].x = hi.z; ea2[s * 4 + 3].y = hi.w;
        }
    }
    v2f hiv2, ei2;             // (l=m, l=m+16) pairs for stage C
    hiv2.x = bf2f(wsu[U_HJB + i * 32 + m]);      hiv2.y = bf2f(wsu[U_HJB + i * 32 + 16 + m]);
    ei2.x = ws[WS_CI + i * 32 + m];              ei2.y = ws[WS_CI + i * 32 + 16 + m];
    const float aggi = ws[WS_AGG + i];
    const float sub0 = (sub == 0) ? 1.0f : 0.0f;

    // ---- streaming pointers + tile-0 prefetch ----
    const unsigned short* hp = wsu + U_HJB + (jw + (lane >> 2)) * 32 + sub * 8;
    const unsigned short* bp = wsu + U_BJB + (jw + m) * 64 + q * 8;
    const unsigned short* jp = wsu + U_JT + ((jw + q * 4) * 16 + m) * 8;

    uint4 hvA = *(const uint4*)hp;
    uint4 b0A = *(const uint4*)bp;
    uint4 b1A = *(const uint4*)(bp + 32);
    uint4 hvB, b0B, b1B;
    __syncthreads();

    // persistent accumulators
    f32x4 accK[2];
    #pragma unroll
    for (int lb = 0; lb < 2; lb++) { accK[lb][0]=0.f; accK[lb][1]=0.f; accK[lb][2]=0.f; accK[lb][3]=0.f; }
    v2f u2; u2.x = 0.f; u2.y = 0.f;
    v2f vv2; vv2.x = 0.f; vv2.y = 0.f;
    float sumfac = 0.f;

    unsigned short* xb0 = &x2ls[w * 2 * 1152];
    unsigned short* xb1 = xb0 + 1152;

    auto stageB = [&](const unsigned short* xb) {
        bf16x8 x2f[2];
        #pragma unroll
        for (int s = 0; s < 2; s++)
            x2f[s] = *(const bf16x8*)(&xb[m * 72 + s * 32 + q * 8]);
        #pragma unroll
        for (int lb = 0; lb < 2; lb++) {
            #pragma unroll
            for (int s = 0; s < 2; s++) {
                bf16x8 w3f = *(const bf16x8*)(&W3ls[(lb * 16 + m) * 72 + s * 32 + q * 8]);
                accK[lb] = __builtin_amdgcn_mfma_f32_16x16x32_bf16(x2f[s], w3f, accK[lb], 0, 0, 0);
            }
        }
    };

    auto body = [&](int T, uint4 hvc, uint4 b0c, uint4 b1c,
                    uint4& hvn, uint4& b0n, uint4& b1n,
                    unsigned short* xcur, const unsigned short* xprev) {
        // prefetch next tile's h/b
        hp += 2048; bp += 4096;
        hvn = *(const uint4*)hp;
        b0n = *(const uint4*)bp;
        b1n = *(const uint4*)(bp + 32);

        // deferred stage B for previous tile (LDS data a full body old)
        if (T > 0) stageB(xprev);

        // 1) fac (lane owns j = T*64 + jw + (lane>>2)); zeroed at j==i
        float facm;
        {
            unsigned int hd[4] = {hvc.x, hvc.y, hvc.z, hvc.w};
            v2f s2v; s2v.x = 0.f; s2v.y = 0.f;
            #pragma unroll
            for (int e = 0; e < 4; e++) {
                v2f hj; hj.x = blo(hd[e]); hj.y = bhi(hd[e]);
                v2f d = hi2[e] - hj;
                s2v += d * d;                      // v_pk_fma
            }
            float s = s2v.x + s2v.y;
            s += __shfl_xor(s, 1); s += __shfl_xor(s, 2);
            int jj = T * 64 + jw + (lane >> 2);
            float facown = fminf(__builtin_amdgcn_rsqf(s), 2.0f) * aggi;
            facown = (jj == i) ? 0.0f : facown;
            sumfac = fmaf(sub0, facown, sumfac);
            facm = __shfl(facown, 4 * m);
        }
        const float fm2 = -2.0f * facm;

        // 2) x1 B-fragments: factored paired tanh (pk fma, shared rcp, NO exp2)
        bf16x8 afr[2];
        {
            unsigned int bd[8] = {b0c.x, b0c.y, b0c.z, b0c.w, b1c.x, b1c.y, b1c.z, b1c.w};
            #pragma unroll
            for (int s = 0; s < 2; s++) {
                union { uint4 u4; bf16x8 v; } pkd;
                #pragma unroll
                for (int e = 0; e < 4; e++) {
                    unsigned int bw = bd[s * 4 + e];
                    v2f eb; eb.x = blo(bw); eb.y = bhi(bw);
                    v2f t2 = tanh2_fact(ea2[s * 4 + e], eb);
                    ((unsigned int*)&pkd.u4)[e] = pk2(t2.x, t2.y);
                }
                afr[s] = pkd.v;
            }
        }

        // jt loads for CURRENT tile (consumed in stage C; latency hidden
        // under stage A MFMA + epilogue)
        uint4 jt4[4];
        #pragma unroll
        for (int r = 0; r < 4; r++) jt4[r] = *(const uint4*)(jp + r * 128);
        jp += 8192;

        // 3) stage A: X2^T = Wi2' * X1^T, C-init = scaled bias
        f32x4 accA[4];
        #pragma unroll
        for (int nb = 0; nb < 4; nb++) {
            f32x4 acc = b2q[nb];
            #pragma unroll
            for (int s = 0; s < 2; s++) {
                bf16x8 w2f = *(const bf16x8*)(&W2ls[(nb * 16 + m) * 72 + s * 32 + q * 8]);
                acc = __builtin_amdgcn_mfma_f32_16x16x32_bf16(w2f, afr[s], acc, 0, 0, 0);
            }
            accA[nb] = acc;
        }
        // epilogue A: x2s = fma(fm2, rcp(exp2(acc)+1), facm), paired rcp
        #pragma unroll
        for (int nb = 0; nb < 4; nb++) {
            v2f eA; eA.x = __builtin_amdgcn_exp2f(accA[nb][0]); eA.y = __builtin_amdgcn_exp2f(accA[nb][1]);
            v2f eB; eB.x = __builtin_amdgcn_exp2f(accA[nb][2]); eB.y = __builtin_amdgcn_exp2f(accA[nb][3]);
            v2f dA = eA + 1.0f, dB = eB + 1.0f;
            float rA = fast_rcp(dA.x * dA.y), rB = fast_rcp(dB.x * dB.y);
            v2f swA; swA.x = dA.y; swA.y = dA.x;
            v2f swB; swB.x = dB.y; swB.y = dB.x;
            v2f rvA = swA * rA, rvB = swB * rB;      // rcp of each element
            v2f tA = rvA * fm2 + facm;
            v2f tB = rvB * fm2 + facm;
            uint2 pk; pk.x = pk2(tA.x, tA.y); pk.y = pk2(tB.x, tB.y);
            *(uint2*)(&xcur[m * 72 + nb * 16 + q * 4]) = pk;
        }

        // 5) stage C: quantum partials; coh = rcp(1 + Ei*Ej) (pk fma, no exp2)
        #pragma unroll
        for (int r = 0; r < 4; r++) {
            uint4 jv = jt4[r];
            v2f hj2; hj2.x = blo(jv.x); hj2.y = bhi(jv.x);
            v2f ej2; ej2.x = blo(jv.y); ej2.y = bhi(jv.y);
            v2f pc2; pc2.x = blo(jv.z); pc2.y = bhi(jv.z);
            v2f ps2; ps2.x = blo(jv.w); ps2.y = bhi(jv.w);
            v2f dd = ei2 * ej2 + 1.0f;
            float rr = fast_rcp(dd.x * dd.y);
            v2f swd; swd.x = dd.y; swd.y = dd.x;
            v2f coh = swd * rr;                    // sigmoid of each element
            v2f cd = coh * (hiv2 - hj2);
            u2  += cd * pc2;
            vv2 += cd * ps2;
        }
    };

    #pragma unroll 1
    for (int T = 0; T < 16; T += 2) {
        body(T,     hvA, b0A, b1A, hvB, b0B, b1B, xb0, xb1);
        body(T + 1, hvB, b0B, b1B, hvA, b0A, b1A, xb1, xb0);
    }
    stageB(xb1);   // tile 15

    // ---- final reductions ----
    float T1[2];
    float aU[2] = {u2.x, u2.y};
    float aV[2] = {vv2.x, vv2.y};
    #pragma unroll
    for (int lb = 0; lb < 2; lb++) {
        T1[lb] = (accK[lb][0] + accK[lb][1]) + (accK[lb][2] + accK[lb][3]);
        T1[lb] += __shfl_xor(T1[lb], 16); T1[lb] += __shfl_xor(T1[lb], 32);
        aU[lb] += __shfl_xor(aU[lb], 16); aU[lb] += __shfl_xor(aU[lb], 32);
        aV[lb] += __shfl_xor(aV[lb], 16); aV[lb] += __shfl_xor(aV[lb], 32);
    }
    sumfac += __shfl_xor(sumfac, 1);  sumfac += __shfl_xor(sumfac, 2);
    sumfac += __shfl_xor(sumfac, 4);  sumfac += __shfl_xor(sumfac, 8);
    sumfac += __shfl_xor(sumfac, 16); sumfac += __shfl_xor(sumfac, 32);
    if (lane < 16) {
        redT[w][m] = T1[0];      redT[w][16 + m] = T1[1];
        redU[w][m] = aU[0];      redU[w][16 + m] = aU[1];
        redV[w][m] = aV[0];      redV[w][16 + m] = aV[1];
    }
    if (lane == 0) sfw[w] = sumfac;
    __syncthreads();
    if (tid < 32) {
        int l = tid;
        float t1 = (redT[0][l] + redT[1][l]) + (redT[2][l] + redT[3][l]);
        float uu = (redU[0][l] + redU[1][l]) + (redU[2][l] + redU[3][l]);
        float vvv = (redV[0][l] + redV[1][l]) + (redV[2][l] + redV[3][l]);
        float sf = (sfw[0] + sfw[1]) + (sfw[2] + sfw[3]);
        int mm = l & 15;
        uint2 jti = *(const uint2*)(wsu + U_JT + (i * 16 + mm) * 8 + 4);  // cc/sc pair words
        float pic = (l < 16) ? blo(jti.x) : bhi(jti.x);
        float pis = (l < 16) ? blo(jti.y) : bhi(jti.y);
        float isum = t1 + sf * ws[WS_BI3 + l] - (pic * uu + pis * vvv);
        out[i * 33 + l] = 0.5f * ws[WS_SELF + i * 32 + l] + 0.3f * isum;
        // parallel |isum| tail reduce (replaces serial tid==0 loop)
        float ab = fabsf(isum);
        ab += __shfl_xor(ab, 1); ab += __shfl_xor(ab, 2);
        ab += __shfl_xor(ab, 4); ab += __shfl_xor(ab, 8);
        ab += __shfl_xor(ab, 16);
        if (tid == 0) out[i * 33 + 32] = 0.1f + 0.05f * ab;
    }
}

extern "C" void kernel_launch(void* const* d_in, const int* in_sizes, int n_in,
                              void* d_out, int out_size, void* d_ws, size_t ws_size,
                              hipStream_t stream) {
    const float* state   = (const float*)d_in[0];
    const float* Ws1     = (const float*)d_in[1];
    const float* bs1     = (const float*)d_in[2];
    const float* Ws2     = (const float*)d_in[3];
    const float* bs2     = (const float*)d_in[4];
    const float* Ws3     = (const float*)d_in[5];
    const float* bs3     = (const float*)d_in[6];
    const float* Wi1     = (const float*)d_in[7];
    const float* bi1     = (const float*)d_in[8];
    const float* Wi2     = (const float*)d_in[9];
    const float* bi2     = (const float*)d_in[10];
    const float* Wi3     = (const float*)d_in[11];
    const float* bi3     = (const float*)d_in[12];
    const float* phase_w = (const float*)d_in[13];
    const float* Wc      = (const float*)d_in[14];
    const float* bc      = (const float*)d_in[15];
    const float* aggr    = (const float*)d_in[16];

    float* ws = (float*)d_ws;
    unsigned short* wsu = (unsigned short*)(ws + WS_FEND);
    float* out = (float*)d_out;

    precompute<<<256, 256, 0, stream>>>(state, Ws1, bs1, Ws2, bs2, Ws3, bs3,
                                        Wi1, bi1, Wi2, bi2, Wi3, bi3,
                                        phase_w, Wc, bc, aggr, ws, wsu);
    pair_kernel<<<NN, 256, 0, stream>>>(ws, wsu, out);
}

// Round 4
// 141.587 us; speedup vs baseline: 1.7599x; 1.0127x over previous
//
#include <hip/hip_runtime.h>
#include <hip/hip_bf16.h>
#include <math.h>

#define NN 1024
#define LDIM 32
#define HDIM 64

// ---------------- fp32 workspace layout (float offsets) ----------------
#define WS_SELF 0                        // N*L   self_term [i][l]
#define WS_AA   (WS_SELF + NN*LDIM)      // N*H   Ea = 2^(2log2e * a_i) [i][h]
#define WS_CI   (WS_AA   + NN*HDIM)      // N*L   Ei = 2^(-log2e*(ci+bc)) [i][l]
#define WS_AGG  (WS_CI   + NN*LDIM)      // N     sigmoid(aggr)
#define WS_BI2  (WS_AGG  + NN)           // H     bi2 (UNSCALED - Pade epilogue)
#define WS_BI3  (WS_BI2  + HDIM)         // L     bi3 (unscaled)
#define WS_JT   (WS_BI3  + LDIM)         // N*16*8 f32 {h0,h1,Ej0,Ej1}{pc0,pc1,ps0,ps1}
#define WS_F32END (WS_JT + NN*16*8)

// ---------------- bf16(u16) region (short offsets from wsu) -------------
#define U_BJB  0                         // N*H   Eb = 2^(2log2e * b_j) [j][h]
#define U_HJB  (U_BJB + NN*HDIM)         // N*L   h   [j][l]
#define U_W2B  (U_HJB + NN*LDIM)         // H*H   Wi2 [n][k] (UNSCALED)
#define U_W3B  (U_W2B + HDIM*HDIM)       // L*H   Wi3 [l][k] (unscaled)
#define U_END  (U_W3B + LDIM*HDIM)

// packed-pair transposed weight tables in precompute LDS (uint offsets)
#define PK_W1  0        // 16*64   Ws1
#define PK_W2  1024     // 32*64   Ws2
#define PK_W3  3072     // 32*32   Ws3
#define PK_WI1 4096     // 64*64   Wi1
#define PK_WC  8192     // 32*32   Wc
#define PK_END 9216     // 36 KB

#define K2P  2.88539008f     // 2*log2(e)
#define K1N  (-1.44269504f)  // -log2(e)

typedef __attribute__((ext_vector_type(8))) short bf16x8;
typedef __attribute__((ext_vector_type(4))) float f32x4;
typedef __attribute__((ext_vector_type(2))) float v2f;

__device__ __forceinline__ float fast_rcp(float x) { return __builtin_amdgcn_rcpf(x); }
__device__ __forceinline__ float fast_tanh(float x) {          // full version (precompute)
    float e = __builtin_amdgcn_exp2f(x * K2P);
    return 1.0f - 2.0f * fast_rcp(e + 1.0f);
}
__device__ __forceinline__ float fast_sigmoid(float x) {       // full version (precompute)
    return fast_rcp(1.0f + __builtin_amdgcn_exp2f(x * K1N));
}
__device__ __forceinline__ float blo(unsigned int u) { union { unsigned int i; float f; } v; v.i = u << 16; return v.f; }
__device__ __forceinline__ float bhi(unsigned int u) { union { unsigned int i; float f; } v; v.i = u & 0xffff0000u; return v.f; }
__device__ __forceinline__ float bf2f(unsigned short u) { union { unsigned int i; float f; } v; v.i = ((unsigned int)u) << 16; return v.f; }
__device__ __forceinline__ unsigned short f2bf(float f) {
    __hip_bfloat16 b = __float2bfloat16(f);
    unsigned short u; __builtin_memcpy(&u, &b, 2); return u;
}
__device__ __forceinline__ unsigned int pk2(float a, float b) {
    float2 t; t.x = a; t.y = b;
    __hip_bfloat162 h = __float22bfloat162_rn(t);
    unsigned int u; __builtin_memcpy(&u, &h, 4); return u;
}

// factored paired tanh: tanh of pre-scaled (p_i + q_j) where Ea = 2^p (f32
// reg, loop-invariant) and Eb = 2^q (streamed bf16). d = Ea*Eb + 1 is one
// pk-fma -- no exp2 in the inner loop. Shared rcp for the pair.
__device__ __forceinline__ v2f tanh2_fact(v2f ea, v2f eb) {
    v2f d = ea * eb + 1.0f;
    float rr = fast_rcp(d.x * d.y);
    v2f sw; sw.x = d.y; sw.y = d.x;
    v2f r = sw * rr;                 // r_k = rcp(d_k)
    return 1.0f - 2.0f * r;
}

// ------------- kernel 1: precompute (weights packed in-block) -------------
__global__ __launch_bounds__(256) void precompute(
    const float* __restrict__ state,
    const float* __restrict__ Ws1, const float* __restrict__ bs1,
    const float* __restrict__ Ws2, const float* __restrict__ bs2,
    const float* __restrict__ Ws3, const float* __restrict__ bs3,
    const float* __restrict__ Wi1, const float* __restrict__ bi1,
    const float* __restrict__ Wi2, const float* __restrict__ bi2,
    const float* __restrict__ Wi3, const float* __restrict__ bi3,
    const float* __restrict__ phw, const float* __restrict__ Wc,
    const float* __restrict__ bc,  const float* __restrict__ aggr,
    float* __restrict__ ws, unsigned short* __restrict__ wsu) {
    const int tid = threadIdx.x;
    const int w = tid >> 6, t = tid & 63;
    const int i = blockIdx.x * 4 + w;

    __shared__ unsigned int wlds[PK_END];
    __shared__ float shh[4][32], shdh[4][32], sht1[4][64], sht2[4][64];
    __shared__ float shph[4];

    {
        const float2* s1 = (const float2*)Ws1;
        #pragma unroll
        for (int r = 0; r < 4; r++) { int e = tid + r * 256; int f = e >> 4, k2 = e & 15;
            float2 v = s1[e]; wlds[PK_W1 + k2 * 64 + f] = pk2(v.x, v.y); }
        const float2* s2 = (const float2*)Ws2;
        #pragma unroll
        for (int r = 0; r < 8; r++) { int e = tid + r * 256; int f = e >> 5, k2 = e & 31;
            float2 v = s2[e]; wlds[PK_W2 + k2 * 64 + f] = pk2(v.x, v.y); }
        const float2* s3 = (const float2*)Ws3;
        #pragma unroll
        for (int r = 0; r < 4; r++) { int e = tid + r * 256; int f = e >> 5, k2 = e & 31;
            float2 v = s3[e]; wlds[PK_W3 + k2 * 32 + f] = pk2(v.x, v.y); }
        const float2* si = (const float2*)Wi1;
        #pragma unroll
        for (int r = 0; r < 16; r++) { int e = tid + r * 256; int f = e >> 6, c2 = e & 63;
            float2 v = si[e]; wlds[PK_WI1 + c2 * 64 + f] = pk2(v.x, v.y); }
        const float2* sc = (const float2*)Wc;
        #pragma unroll
        for (int r = 0; r < 4; r++) { int e = tid + r * 256; int f = e >> 5, c2 = e & 31;
            float2 v = sc[e]; wlds[PK_WC + c2 * 32 + f] = pk2(v.x, v.y); }
    }
    if (blockIdx.x == 0) {
        // Wi2/bi2 UNSCALED: pair epilogue uses Pade tanh, not exp2
        #pragma unroll
        for (int r = 0; r < 16; r++) { int e = tid + r * 256; wsu[U_W2B + e] = f2bf(Wi2[e]); }
        #pragma unroll
        for (int r = 0; r < 8; r++)  { int e = tid + r * 256; wsu[U_W3B + e] = f2bf(Wi3[e]); }
        if (tid < HDIM) ws[WS_BI2 + tid] = bi2[tid];
        if (tid < LDIM) ws[WS_BI3 + tid] = bi3[tid];
    }

    float sv = (t < 33) ? state[i * 33 + t] : 0.f;
    if (t < 32) shh[w][t] = sv;
    if (t == 32) shph[w] = sv;
    if (t == 33) ws[WS_AGG + i] = fast_sigmoid(aggr[i]);
    __syncthreads();

    {
        float s = bs1[t];
        const unsigned int* W = wlds + PK_W1;
        #pragma unroll
        for (int k2 = 0; k2 < 16; k2++) {
            unsigned int p = W[k2 * 64 + t];
            s = fmaf(blo(p), shh[w][2 * k2], s);
            s = fmaf(bhi(p), shh[w][2 * k2 + 1], s);
        }
        sht1[w][t] = fast_tanh(s);
    }
    __syncthreads();
    {
        float s = bs2[t];
        const unsigned int* W = wlds + PK_W2;
        #pragma unroll
        for (int k2 = 0; k2 < 32; k2++) {
            unsigned int p = W[k2 * 64 + t];
            s = fmaf(blo(p), sht1[w][2 * k2], s);
            s = fmaf(bhi(p), sht1[w][2 * k2 + 1], s);
        }
        sht2[w][t] = fast_tanh(s);
    }
    __syncthreads();
    if (t < 32) {
        float s = bs3[t];
        const unsigned int* W = wlds + PK_W3;
        #pragma unroll
        for (int k2 = 0; k2 < 32; k2++) {
            unsigned int p = W[k2 * 32 + t];
            s = fmaf(blo(p), sht2[w][2 * k2], s);
            s = fmaf(bhi(p), sht2[w][2 * k2 + 1], s);
        }
        ws[WS_SELF + i * 32 + t] = s;
        shdh[w][t] = s;
    }
    __syncthreads();
    {
        float sa = 0.f, sb = bi1[t];
        const unsigned int* W = wlds + PK_WI1;
        #pragma unroll
        for (int k2 = 0; k2 < 16; k2++) {
            float h0 = shh[w][2 * k2], h1 = shh[w][2 * k2 + 1];
            float d0 = shdh[w][2 * k2], d1 = shdh[w][2 * k2 + 1];
            unsigned int wa  = W[k2 * 64 + t];
            unsigned int wb  = W[(16 + k2) * 64 + t];
            unsigned int wa2 = W[(32 + k2) * 64 + t];
            unsigned int wb2 = W[(48 + k2) * 64 + t];
            sa = fmaf(blo(wa), h0, sa);  sa = fmaf(bhi(wa), h1, sa);
            sb = fmaf(blo(wb), h0, sb);  sb = fmaf(bhi(wb), h1, sb);
            sa = fmaf(blo(wa2), d0, sa); sa = fmaf(bhi(wa2), d1, sa);
            sb = fmaf(blo(wb2), d0, sb); sb = fmaf(bhi(wb2), d1, sb);
        }
        // exp-factorized: store E = 2^(pre-scaled logit) instead of logit
        ws[WS_AA + i * 64 + t]  = __builtin_amdgcn_exp2f(sa * K2P);
        wsu[U_BJB + i * 64 + t] = f2bf(__builtin_amdgcn_exp2f(sb * K2P));
    }
    if (t < 32) {
        float si2 = 0.f, sj = 0.f;
        const unsigned int* W = wlds + PK_WC;
        #pragma unroll
        for (int m2 = 0; m2 < 16; m2++) {
            float h0 = shh[w][2 * m2], h1 = shh[w][2 * m2 + 1];
            unsigned int wi = W[m2 * 32 + t];
            unsigned int wj = W[(16 + m2) * 32 + t];
            si2 = fmaf(blo(wi), h0, si2); si2 = fmaf(bhi(wi), h1, si2);
            sj  = fmaf(blo(wj), h0, sj);  sj  = fmaf(bhi(wj), h1, sj);
        }
        // Ei = 2^(-log2e*(ci+bc)); sigmoid(ci+cj) = rcp(1 + Ei*Ej)
        ws[WS_CI + i * 32 + t] = __builtin_amdgcn_exp2f((si2 + bc[t]) * K1N);
        float h = shh[w][t];
        wsu[U_HJB + i * 32 + t] = f2bf(h);
        float ejn = __builtin_amdgcn_exp2f(sj * K1N);
        float sc_, cc_;
        __sincosf(shph[w] * phw[t], &sc_, &cc_);
        // pair (l, l+16) into two f32 float4s for unpack-free stage C
        int p = (t & 15) + 16;                       // partner lane (self for t>=16)
        float h_p  = __shfl(h,   p);
        float e_p  = __shfl(ejn, p);
        float cc_p = __shfl(cc_, p);
        float sc_p = __shfl(sc_, p);
        if (t < 16) {
            float4 o0; o0.x = h;   o0.y = h_p;  o0.z = ejn; o0.w = e_p;
            float4 o1; o1.x = cc_; o1.y = cc_p; o1.z = sc_; o1.w = sc_p;
            *(float4*)(ws + WS_JT + (i * 16 + t) * 8)     = o0;
            *(float4*)(ws + WS_JT + (i * 16 + t) * 8 + 4) = o1;
        }
    }
}

// ------------- kernel 2: MFMA pairwise core (1 block per i) ---------------
// Diet v4: (a) Pade(15,6) tanh epilogue -- logit z = Wi2.x1+bi2 has
// sigma~0.2 so |z|<~1.3; Pade abs err <= 2e-3 < bf16 rounding of the x2s
// store. Removes 16 quarter-rate exp2/tile. (b) stage-C JT stream in f32
// (two float4s) -- removes 32 bf16 unpacks/tile. Trans ops/tile 37 -> 21.
// Occupancy: grid-limited 4 blocks/CU; VGPR budget free up to 128.
__global__ __launch_bounds__(256) void pair_kernel(
    const float* __restrict__ ws, const unsigned short* __restrict__ wsu,
    float* __restrict__ out) {
    const int i    = blockIdx.x;
    const int tid  = threadIdx.x;
    const int w    = tid >> 6;
    const int lane = tid & 63;
    const int q    = lane >> 4;
    const int m    = lane & 15;
    const int jw   = w * 16;
    const int sub  = lane & 3;

    __shared__ unsigned short W2ls[64 * 72];
    __shared__ unsigned short W3ls[32 * 72];
    __shared__ unsigned short x2ls[4 * 2 * 16 * 72];   // per-wave double buffer
    __shared__ float redT[4][32], redU[4][32], redV[4][32];
    __shared__ float sfw[4];

    // ---- setup ----
    {
        int row = tid >> 2, c = (tid & 3) * 16;
        const uint4* s2 = (const uint4*)(wsu + U_W2B + row * 64 + c);
        uint4 d0 = s2[0], d1 = s2[1];
        uint4* dd = (uint4*)(&W2ls[row * 72 + c]);
        dd[0] = d0; dd[1] = d1;
        if (row < 32) {
            const uint4* s3 = (const uint4*)(wsu + U_W3B + row * 64 + c);
            uint4 e0 = s3[0], e1 = s3[1];
            uint4* d3 = (uint4*)(&W3ls[row * 72 + c]);
            d3[0] = e0; d3[1] = e1;
        }
    }
    v2f hi2[4];                     // own h pairs for fac
    {
        uint4 hv4 = *(const uint4*)(wsu + U_HJB + i * 32 + sub * 8);
        unsigned int hd[4] = {hv4.x, hv4.y, hv4.z, hv4.w};
        #pragma unroll
        for (int e = 0; e < 4; e++) { hi2[e].x = blo(hd[e]); hi2[e].y = bhi(hd[e]); }
    }
    f32x4 b2q[4];              // bias slice for MFMA C-init (unscaled)
    #pragma unroll
    for (int nb = 0; nb < 4; nb++) {
        float4 bv = *(const float4*)(ws + WS_BI2 + nb * 16 + q * 4);
        b2q[nb][0] = bv.x; b2q[nb][1] = bv.y; b2q[nb][2] = bv.z; b2q[nb][3] = bv.w;
    }
    // Ea = 2^(pre-scaled a_i): loop-invariant across all tiles, in registers
    v2f ea2[8];
    {
        const float* ap = ws + WS_AA + i * 64 + q * 8;
        #pragma unroll
        for (int s = 0; s < 2; s++) {
            float4 lo = *(const float4*)(ap + s * 32);
            float4 hi = *(const float4*)(ap + s * 32 + 4);
            ea2[s * 4 + 0].x = lo.x; ea2[s * 4 + 0].y = lo.y;
            ea2[s * 4 + 1].x = lo.z; ea2[s * 4 + 1].y = lo.w;
            ea2[s * 4 + 2].x = hi.x; ea2[s * 4 + 2].y = hi.y;
            ea2[s * 4 + 3].x = hi.z; ea2[s * 4 + 3].y = hi.w;
        }
    }
    v2f hiv2, ei2;             // (l=m, l=m+16) pairs for stage C
    hiv2.x = bf2f(wsu[U_HJB + i * 32 + m]);      hiv2.y = bf2f(wsu[U_HJB + i * 32 + 16 + m]);
    ei2.x = ws[WS_CI + i * 32 + m];              ei2.y = ws[WS_CI + i * 32 + 16 + m];
    const float aggi = ws[WS_AGG + i];
    const float sub0 = (sub == 0) ? 1.0f : 0.0f;

    // ---- streaming pointers + tile-0 prefetch ----
    const unsigned short* hp = wsu + U_HJB + (jw + (lane >> 2)) * 32 + sub * 8;
    const unsigned short* bp = wsu + U_BJB + (jw + m) * 64 + q * 8;
    const float* jp = ws + WS_JT + ((jw + q * 4) * 16 + m) * 8;

    uint4 hvA = *(const uint4*)hp;
    uint4 b0A = *(const uint4*)bp;
    uint4 b1A = *(const uint4*)(bp + 32);
    uint4 hvB, b0B, b1B;
    __syncthreads();

    // persistent accumulators
    f32x4 accK[2];
    #pragma unroll
    for (int lb = 0; lb < 2; lb++) { accK[lb][0]=0.f; accK[lb][1]=0.f; accK[lb][2]=0.f; accK[lb][3]=0.f; }
    v2f u2; u2.x = 0.f; u2.y = 0.f;
    v2f vv2; vv2.x = 0.f; vv2.y = 0.f;
    float sumfac = 0.f;

    unsigned short* xb0 = &x2ls[w * 2 * 1152];
    unsigned short* xb1 = xb0 + 1152;

    auto stageB = [&](const unsigned short* xb) {
        bf16x8 x2f[2];
        #pragma unroll
        for (int s = 0; s < 2; s++)
            x2f[s] = *(const bf16x8*)(&xb[m * 72 + s * 32 + q * 8]);
        #pragma unroll
        for (int lb = 0; lb < 2; lb++) {
            #pragma unroll
            for (int s = 0; s < 2; s++) {
                bf16x8 w3f = *(const bf16x8*)(&W3ls[(lb * 16 + m) * 72 + s * 32 + q * 8]);
                accK[lb] = __builtin_amdgcn_mfma_f32_16x16x32_bf16(x2f[s], w3f, accK[lb], 0, 0, 0);
            }
        }
    };

    auto body = [&](int T, uint4 hvc, uint4 b0c, uint4 b1c,
                    uint4& hvn, uint4& b0n, uint4& b1n,
                    unsigned short* xcur, const unsigned short* xprev) {
        // prefetch next tile's h/b
        hp += 2048; bp += 4096;
        hvn = *(const uint4*)hp;
        b0n = *(const uint4*)bp;
        b1n = *(const uint4*)(bp + 32);

        // deferred stage B for previous tile (LDS data a full body old)
        if (T > 0) stageB(xprev);

        // 1) fac (lane owns j = T*64 + jw + (lane>>2)); zeroed at j==i
        float facm;
        {
            unsigned int hd[4] = {hvc.x, hvc.y, hvc.z, hvc.w};
            v2f s2v; s2v.x = 0.f; s2v.y = 0.f;
            #pragma unroll
            for (int e = 0; e < 4; e++) {
                v2f hj; hj.x = blo(hd[e]); hj.y = bhi(hd[e]);
                v2f d = hi2[e] - hj;
                s2v += d * d;                      // v_pk_fma
            }
            float s = s2v.x + s2v.y;
            s += __shfl_xor(s, 1); s += __shfl_xor(s, 2);
            int jj = T * 64 + jw + (lane >> 2);
            float facown = fminf(__builtin_amdgcn_rsqf(s), 2.0f) * aggi;
            facown = (jj == i) ? 0.0f : facown;
            sumfac = fmaf(sub0, facown, sumfac);
            facm = __shfl(facown, 4 * m);
        }

        // 2) x1 B-fragments: factored paired tanh (pk fma, shared rcp, NO exp2)
        bf16x8 afr[2];
        {
            unsigned int bd[8] = {b0c.x, b0c.y, b0c.z, b0c.w, b1c.x, b1c.y, b1c.z, b1c.w};
            #pragma unroll
            for (int s = 0; s < 2; s++) {
                union { uint4 u4; bf16x8 v; } pkd;
                #pragma unroll
                for (int e = 0; e < 4; e++) {
                    unsigned int bw = bd[s * 4 + e];
                    v2f eb; eb.x = blo(bw); eb.y = bhi(bw);
                    v2f t2 = tanh2_fact(ea2[s * 4 + e], eb);
                    ((unsigned int*)&pkd.u4)[e] = pk2(t2.x, t2.y);
                }
                afr[s] = pkd.v;
            }
        }

        // jt loads for CURRENT tile (f32, unpack-free; consumed in stage C;
        // latency hidden under stage A MFMA + epilogue)
        float4 jf0[4], jf1[4];
        #pragma unroll
        for (int r = 0; r < 4; r++) {
            jf0[r] = *(const float4*)(jp + r * 128);
            jf1[r] = *(const float4*)(jp + r * 128 + 4);
        }
        jp += 8192;

        // 3) stage A: X2^T = Wi2' * X1^T, C-init = bias (unscaled logit out)
        f32x4 accA[4];
        #pragma unroll
        for (int nb = 0; nb < 4; nb++) {
            f32x4 acc = b2q[nb];
            #pragma unroll
            for (int s = 0; s < 2; s++) {
                bf16x8 w2f = *(const bf16x8*)(&W2ls[(nb * 16 + m) * 72 + s * 32 + q * 8]);
                acc = __builtin_amdgcn_mfma_f32_16x16x32_bf16(w2f, afr[s], acc, 0, 0, 0);
            }
            accA[nb] = acc;
        }
        // epilogue A: x2s = facm * tanh(z) via Pade(15,6): z(15+z^2)/(15+6z^2)
        // |z| <= ~1.3 (6 sigma) -> abs err <= 2e-3, below bf16 store rounding.
        #pragma unroll
        for (int nb = 0; nb < 4; nb++) {
            v2f zA; zA.x = accA[nb][0]; zA.y = accA[nb][1];
            v2f zB; zB.x = accA[nb][2]; zB.y = accA[nb][3];
            v2f zzA = zA * zA, zzB = zB * zB;
            v2f nA = zA * (zzA + 15.0f), nB = zB * (zzB + 15.0f);
            v2f dA = zzA * 6.0f + 15.0f, dB = zzB * 6.0f + 15.0f;
            float rA = fast_rcp(dA.x * dA.y) * facm;   // fold fac into shared rcp
            float rB = fast_rcp(dB.x * dB.y) * facm;
            v2f swA; swA.x = dA.y; swA.y = dA.x;
            v2f swB; swB.x = dB.y; swB.y = dB.x;
            v2f tA = nA * (swA * rA);
            v2f tB = nB * (swB * rB);
            uint2 pk; pk.x = pk2(tA.x, tA.y); pk.y = pk2(tB.x, tB.y);
            *(uint2*)(&xcur[m * 72 + nb * 16 + q * 4]) = pk;
        }

        // 5) stage C: quantum partials; coh = rcp(1 + Ei*Ej) (pk fma, no exp2)
        #pragma unroll
        for (int r = 0; r < 4; r++) {
            v2f hj2; hj2.x = jf0[r].x; hj2.y = jf0[r].y;
            v2f ej2; ej2.x = jf0[r].z; ej2.y = jf0[r].w;
            v2f pc2; pc2.x = jf1[r].x; pc2.y = jf1[r].y;
            v2f ps2; ps2.x = jf1[r].z; ps2.y = jf1[r].w;
            v2f dd = ei2 * ej2 + 1.0f;
            float rr = fast_rcp(dd.x * dd.y);
            v2f swd; swd.x = dd.y; swd.y = dd.x;
            v2f coh = swd * rr;                    // sigmoid of each element
            v2f cd = coh * (hiv2 - hj2);
            u2  += cd * pc2;
            vv2 += cd * ps2;
        }
    };

    #pragma unroll 1
    for (int T = 0; T < 16; T += 2) {
        body(T,     hvA, b0A, b1A, hvB, b0B, b1B, xb0, xb1);
        body(T + 1, hvB, b0B, b1B, hvA, b0A, b1A, xb1, xb0);
    }
    stageB(xb1);   // tile 15

    // ---- final reductions ----
    float T1[2];
    float aU[2] = {u2.x, u2.y};
    float aV[2] = {vv2.x, vv2.y};
    #pragma unroll
    for (int lb = 0; lb < 2; lb++) {
        T1[lb] = (accK[lb][0] + accK[lb][1]) + (accK[lb][2] + accK[lb][3]);
        T1[lb] += __shfl_xor(T1[lb], 16); T1[lb] += __shfl_xor(T1[lb], 32);
        aU[lb] += __shfl_xor(aU[lb], 16); aU[lb] += __shfl_xor(aU[lb], 32);
        aV[lb] += __shfl_xor(aV[lb], 16); aV[lb] += __shfl_xor(aV[lb], 32);
    }
    sumfac += __shfl_xor(sumfac, 1);  sumfac += __shfl_xor(sumfac, 2);
    sumfac += __shfl_xor(sumfac, 4);  sumfac += __shfl_xor(sumfac, 8);
    sumfac += __shfl_xor(sumfac, 16); sumfac += __shfl_xor(sumfac, 32);
    if (lane < 16) {
        redT[w][m] = T1[0];      redT[w][16 + m] = T1[1];
        redU[w][m] = aU[0];      redU[w][16 + m] = aU[1];
        redV[w][m] = aV[0];      redV[w][16 + m] = aV[1];
    }
    if (lane == 0) sfw[w] = sumfac;
    __syncthreads();
    if (tid < 32) {
        int l = tid;
        float t1 = (redT[0][l] + redT[1][l]) + (redT[2][l] + redT[3][l]);
        float uu = (redU[0][l] + redU[1][l]) + (redU[2][l] + redU[3][l]);
        float vvv = (redV[0][l] + redV[1][l]) + (redV[2][l] + redV[3][l]);
        float sf = (sfw[0] + sfw[1]) + (sfw[2] + sfw[3]);
        int mm = l & 15;
        float4 jtf = *(const float4*)(ws + WS_JT + (i * 16 + mm) * 8 + 4);  // {pc0,pc1,ps0,ps1}
        float pic = (l < 16) ? jtf.x : jtf.y;
        float pis = (l < 16) ? jtf.z : jtf.w;
        float isum = t1 + sf * ws[WS_BI3 + l] - (pic * uu + pis * vvv);
        out[i * 33 + l] = 0.5f * ws[WS_SELF + i * 32 + l] + 0.3f * isum;
        // parallel |isum| tail reduce
        float ab = fabsf(isum);
        ab += __shfl_xor(ab, 1); ab += __shfl_xor(ab, 2);
        ab += __shfl_xor(ab, 4); ab += __shfl_xor(ab, 8);
        ab += __shfl_xor(ab, 16);
        if (tid == 0) out[i * 33 + 32] = 0.1f + 0.05f * ab;
    }
}

extern "C" void kernel_launch(void* const* d_in, const int* in_sizes, int n_in,
                              void* d_out, int out_size, void* d_ws, size_t ws_size,
                              hipStream_t stream) {
    const float* state   = (const float*)d_in[0];
    const float* Ws1     = (const float*)d_in[1];
    const float* bs1     = (const float*)d_in[2];
    const float* Ws2     = (const float*)d_in[3];
    const float* bs2     = (const float*)d_in[4];
    const float* Ws3     = (const float*)d_in[5];
    const float* bs3     = (const float*)d_in[6];
    const float* Wi1     = (const float*)d_in[7];
    const float* bi1     = (const float*)d_in[8];
    const float* Wi2     = (const float*)d_in[9];
    const float* bi2     = (const float*)d_in[10];
    const float* Wi3     = (const float*)d_in[11];
    const float* bi3     = (const float*)d_in[12];
    const float* phase_w = (const float*)d_in[13];
    const float* Wc      = (const float*)d_in[14];
    const float* bc      = (const float*)d_in[15];
    const float* aggr    = (const float*)d_in[16];

    float* ws = (float*)d_ws;
    unsigned short* wsu = (unsigned short*)(ws + WS_F32END);
    float* out = (float*)d_out;

    precompute<<<256, 256, 0, stream>>>(state, Ws1, bs1, Ws2, bs2, Ws3, bs3,
                                        Wi1, bi1, Wi2, bi2, Wi3, bi3,
                                        phase_w, Wc, bc, aggr, ws, wsu);
    pair_kernel<<<NN, 256, 0, stream>>>(ws, wsu, out);
}

// Round 5
// 138.813 us; speedup vs baseline: 1.7951x; 1.0200x over previous
//
#include <hip/hip_runtime.h>
#include <hip/hip_bf16.h>
#include <math.h>

#define NN 1024
#define LDIM 32
#define HDIM 64

// ---------------- fp32 workspace layout (float offsets) ----------------
#define WS_SELF 0                        // N*L   self_term [i][l]
#define WS_AA   (WS_SELF + NN*LDIM)      // N*H   Ea = 2^(2log2e * a_i) [i][h]
#define WS_CI   (WS_AA   + NN*HDIM)      // N*L   Ei = 2^(-log2e*(ci+bc)) [i][l]
#define WS_AGG  (WS_CI   + NN*LDIM)      // N     sigmoid(aggr)
#define WS_BI2  (WS_AGG  + NN)           // H     bi2 (UNSCALED - Pade epilogue)
#define WS_BI3  (WS_BI2  + HDIM)         // L     bi3 (unscaled)
#define WS_FEND (WS_BI3  + LDIM)

// ---------------- bf16(u16) region (short offsets from wsu) -------------
#define U_BJB  0                         // N*H   Eb = 2^(2log2e * b_j) [j][h]
#define U_HJB  (U_BJB + NN*HDIM)         // N*L   h   [j][l]
#define U_JT   (U_HJB + NN*LDIM)         // N*16*8 paired {h0,h1}{Ej0,Ej1}{pc0,pc1}{ps0,ps1}
#define U_W2B  (U_JT  + NN*LDIM*4)       // H*H   Wi2 [n][k] (UNSCALED)
#define U_W3B  (U_W2B + HDIM*HDIM)       // L*H   Wi3 [l][k] (unscaled)
#define U_END  (U_W3B + LDIM*HDIM)

// packed-pair transposed weight tables in precompute LDS (uint offsets)
#define PK_W1  0        // 16*64   Ws1
#define PK_W2  1024     // 32*64   Ws2
#define PK_W3  3072     // 32*32   Ws3
#define PK_WI1 4096     // 64*64   Wi1
#define PK_WC  8192     // 32*32   Wc
#define PK_END 9216     // 36 KB

#define K2P  2.88539008f     // 2*log2(e)
#define K1N  (-1.44269504f)  // -log2(e)

typedef __attribute__((ext_vector_type(8))) short bf16x8;
typedef __attribute__((ext_vector_type(4))) float f32x4;
typedef __attribute__((ext_vector_type(2))) float v2f;

__device__ __forceinline__ float fast_rcp(float x) { return __builtin_amdgcn_rcpf(x); }
__device__ __forceinline__ float fast_tanh(float x) {          // full version (precompute)
    float e = __builtin_amdgcn_exp2f(x * K2P);
    return 1.0f - 2.0f * fast_rcp(e + 1.0f);
}
__device__ __forceinline__ float fast_sigmoid(float x) {       // full version (precompute)
    return fast_rcp(1.0f + __builtin_amdgcn_exp2f(x * K1N));
}
__device__ __forceinline__ float blo(unsigned int u) { union { unsigned int i; float f; } v; v.i = u << 16; return v.f; }
__device__ __forceinline__ float bhi(unsigned int u) { union { unsigned int i; float f; } v; v.i = u & 0xffff0000u; return v.f; }
__device__ __forceinline__ float bf2f(unsigned short u) { union { unsigned int i; float f; } v; v.i = ((unsigned int)u) << 16; return v.f; }
__device__ __forceinline__ unsigned short f2bf(float f) {
    __hip_bfloat16 b = __float2bfloat16(f);
    unsigned short u; __builtin_memcpy(&u, &b, 2); return u;
}
__device__ __forceinline__ unsigned int pk2(float a, float b) {
    float2 t; t.x = a; t.y = b;
    __hip_bfloat162 h = __float22bfloat162_rn(t);
    unsigned int u; __builtin_memcpy(&u, &h, 4); return u;
}

// factored paired tanh: tanh of pre-scaled (p_i + q_j) where Ea = 2^p (f32
// reg, loop-invariant) and Eb = 2^q (streamed bf16). d = Ea*Eb + 1 is one
// pk-fma -- no exp2 in the inner loop. Shared rcp for the pair.
__device__ __forceinline__ v2f tanh2_fact(v2f ea, v2f eb) {
    v2f d = ea * eb + 1.0f;
    float rr = fast_rcp(d.x * d.y);
    v2f sw; sw.x = d.y; sw.y = d.x;
    v2f r = sw * rr;                 // r_k = rcp(d_k)
    return 1.0f - 2.0f * r;
}

// ------------- kernel 1: precompute (weights packed in-block) -------------
__global__ __launch_bounds__(256) void precompute(
    const float* __restrict__ state,
    const float* __restrict__ Ws1, const float* __restrict__ bs1,
    const float* __restrict__ Ws2, const float* __restrict__ bs2,
    const float* __restrict__ Ws3, const float* __restrict__ bs3,
    const float* __restrict__ Wi1, const float* __restrict__ bi1,
    const float* __restrict__ Wi2, const float* __restrict__ bi2,
    const float* __restrict__ Wi3, const float* __restrict__ bi3,
    const float* __restrict__ phw, const float* __restrict__ Wc,
    const float* __restrict__ bc,  const float* __restrict__ aggr,
    float* __restrict__ ws, unsigned short* __restrict__ wsu) {
    const int tid = threadIdx.x;
    const int w = tid >> 6, t = tid & 63;
    const int i = blockIdx.x * 4 + w;

    __shared__ unsigned int wlds[PK_END];
    __shared__ float shh[4][32], shdh[4][32], sht1[4][64], sht2[4][64];
    __shared__ float shph[4];

    {
        const float2* s1 = (const float2*)Ws1;
        #pragma unroll
        for (int r = 0; r < 4; r++) { int e = tid + r * 256; int f = e >> 4, k2 = e & 15;
            float2 v = s1[e]; wlds[PK_W1 + k2 * 64 + f] = pk2(v.x, v.y); }
        const float2* s2 = (const float2*)Ws2;
        #pragma unroll
        for (int r = 0; r < 8; r++) { int e = tid + r * 256; int f = e >> 5, k2 = e & 31;
            float2 v = s2[e]; wlds[PK_W2 + k2 * 64 + f] = pk2(v.x, v.y); }
        const float2* s3 = (const float2*)Ws3;
        #pragma unroll
        for (int r = 0; r < 4; r++) { int e = tid + r * 256; int f = e >> 5, k2 = e & 31;
            float2 v = s3[e]; wlds[PK_W3 + k2 * 32 + f] = pk2(v.x, v.y); }
        const float2* si = (const float2*)Wi1;
        #pragma unroll
        for (int r = 0; r < 16; r++) { int e = tid + r * 256; int f = e >> 6, c2 = e & 63;
            float2 v = si[e]; wlds[PK_WI1 + c2 * 64 + f] = pk2(v.x, v.y); }
        const float2* sc = (const float2*)Wc;
        #pragma unroll
        for (int r = 0; r < 4; r++) { int e = tid + r * 256; int f = e >> 5, c2 = e & 31;
            float2 v = sc[e]; wlds[PK_WC + c2 * 32 + f] = pk2(v.x, v.y); }
    }
    if (blockIdx.x == 0) {
        // Wi2/bi2 UNSCALED: pair epilogue uses Pade tanh, not exp2
        #pragma unroll
        for (int r = 0; r < 16; r++) { int e = tid + r * 256; wsu[U_W2B + e] = f2bf(Wi2[e]); }
        #pragma unroll
        for (int r = 0; r < 8; r++)  { int e = tid + r * 256; wsu[U_W3B + e] = f2bf(Wi3[e]); }
        if (tid < HDIM) ws[WS_BI2 + tid] = bi2[tid];
        if (tid < LDIM) ws[WS_BI3 + tid] = bi3[tid];
    }

    float sv = (t < 33) ? state[i * 33 + t] : 0.f;
    if (t < 32) shh[w][t] = sv;
    if (t == 32) shph[w] = sv;
    if (t == 33) ws[WS_AGG + i] = fast_sigmoid(aggr[i]);
    __syncthreads();

    {
        float s = bs1[t];
        const unsigned int* W = wlds + PK_W1;
        #pragma unroll
        for (int k2 = 0; k2 < 16; k2++) {
            unsigned int p = W[k2 * 64 + t];
            s = fmaf(blo(p), shh[w][2 * k2], s);
            s = fmaf(bhi(p), shh[w][2 * k2 + 1], s);
        }
        sht1[w][t] = fast_tanh(s);
    }
    __syncthreads();
    {
        float s = bs2[t];
        const unsigned int* W = wlds + PK_W2;
        #pragma unroll
        for (int k2 = 0; k2 < 32; k2++) {
            unsigned int p = W[k2 * 64 + t];
            s = fmaf(blo(p), sht1[w][2 * k2], s);
            s = fmaf(bhi(p), sht1[w][2 * k2 + 1], s);
        }
        sht2[w][t] = fast_tanh(s);
    }
    __syncthreads();
    if (t < 32) {
        float s = bs3[t];
        const unsigned int* W = wlds + PK_W3;
        #pragma unroll
        for (int k2 = 0; k2 < 32; k2++) {
            unsigned int p = W[k2 * 32 + t];
            s = fmaf(blo(p), sht2[w][2 * k2], s);
            s = fmaf(bhi(p), sht2[w][2 * k2 + 1], s);
        }
        ws[WS_SELF + i * 32 + t] = s;
        shdh[w][t] = s;
    }
    __syncthreads();
    {
        float sa = 0.f, sb = bi1[t];
        const unsigned int* W = wlds + PK_WI1;
        #pragma unroll
        for (int k2 = 0; k2 < 16; k2++) {
            float h0 = shh[w][2 * k2], h1 = shh[w][2 * k2 + 1];
            float d0 = shdh[w][2 * k2], d1 = shdh[w][2 * k2 + 1];
            unsigned int wa  = W[k2 * 64 + t];
            unsigned int wb  = W[(16 + k2) * 64 + t];
            unsigned int wa2 = W[(32 + k2) * 64 + t];
            unsigned int wb2 = W[(48 + k2) * 64 + t];
            sa = fmaf(blo(wa), h0, sa);  sa = fmaf(bhi(wa), h1, sa);
            sb = fmaf(blo(wb), h0, sb);  sb = fmaf(bhi(wb), h1, sb);
            sa = fmaf(blo(wa2), d0, sa); sa = fmaf(bhi(wa2), d1, sa);
            sb = fmaf(blo(wb2), d0, sb); sb = fmaf(bhi(wb2), d1, sb);
        }
        // exp-factorized: store E = 2^(pre-scaled logit) instead of logit
        ws[WS_AA + i * 64 + t]  = __builtin_amdgcn_exp2f(sa * K2P);
        wsu[U_BJB + i * 64 + t] = f2bf(__builtin_amdgcn_exp2f(sb * K2P));
    }
    if (t < 32) {
        float si2 = 0.f, sj = 0.f;
        const unsigned int* W = wlds + PK_WC;
        #pragma unroll
        for (int m2 = 0; m2 < 16; m2++) {
            float h0 = shh[w][2 * m2], h1 = shh[w][2 * m2 + 1];
            unsigned int wi = W[m2 * 32 + t];
            unsigned int wj = W[(16 + m2) * 32 + t];
            si2 = fmaf(blo(wi), h0, si2); si2 = fmaf(bhi(wi), h1, si2);
            sj  = fmaf(blo(wj), h0, sj);  sj  = fmaf(bhi(wj), h1, sj);
        }
        // Ei = 2^(-log2e*(ci+bc)); sigmoid(ci+cj) = rcp(1 + Ei*Ej)
        ws[WS_CI + i * 32 + t] = __builtin_amdgcn_exp2f((si2 + bc[t]) * K1N);
        float h = shh[w][t];
        wsu[U_HJB + i * 32 + t] = f2bf(h);
        float ejn = __builtin_amdgcn_exp2f(sj * K1N);
        float sc_, cc_;
        __sincosf(shph[w] * phw[t], &sc_, &cc_);
        // pair (l, l+16) into one bf16 uint4 for stage-C pk math
        int p = (t & 15) + 16;                       // partner lane (self for t>=16)
        float h_p  = __shfl(h,   p);
        float e_p  = __shfl(ejn, p);
        float cc_p = __shfl(cc_, p);
        float sc_p = __shfl(sc_, p);
        if (t < 16) {
            uint4 o; o.x = pk2(h, h_p); o.y = pk2(ejn, e_p);
            o.z = pk2(cc_, cc_p); o.w = pk2(sc_, sc_p);
            *(uint4*)(wsu + U_JT + (i * 16 + t) * 8) = o;
        }
    }
}

// ------------- kernel 2: MFMA pairwise core (1 block per i) ---------------
// Diet v5 (latency pass): we are stall-bound, not issue-bound (per-SIMD
// VALU duty ~25%; slot/body ~2100cy vs ~650cy issue demand). Changes:
// (a) JT stream reverted to bf16 (R4's f32-JT doubled jt bytes and paid
//     the Pade win back in load latency -- de-confounded here);
// (b) jt loads hoisted to body TOP: latency cover = stageB+fac+x1+stageA
//     instead of stageA alone;
// (c) W3 fragments hoisted to registers (constant per thread): kills 4
//     ds_read_b128/body on the stageB chain, -4.6KB LDS.
// Occupancy unchanged (grid-limited 4 blocks/CU; >4 waves/SIMD needs
// VGPR<=64 which spills). Target VGPR ~112 < 128 cliff, no pin.
__global__ __launch_bounds__(256) void pair_kernel(
    const float* __restrict__ ws, const unsigned short* __restrict__ wsu,
    float* __restrict__ out) {
    const int i    = blockIdx.x;
    const int tid  = threadIdx.x;
    const int w    = tid >> 6;
    const int lane = tid & 63;
    const int q    = lane >> 4;
    const int m    = lane & 15;
    const int jw   = w * 16;
    const int sub  = lane & 3;

    __shared__ unsigned short W2ls[64 * 72];
    __shared__ unsigned short x2ls[4 * 2 * 16 * 72];   // per-wave double buffer
    __shared__ float redT[4][32], redU[4][32], redV[4][32];
    __shared__ float sfw[4];

    // ---- setup ----
    {
        int row = tid >> 2, c = (tid & 3) * 16;
        const uint4* s2 = (const uint4*)(wsu + U_W2B + row * 64 + c);
        uint4 d0 = s2[0], d1 = s2[1];
        uint4* dd = (uint4*)(&W2ls[row * 72 + c]);
        dd[0] = d0; dd[1] = d1;
    }
    // W3 fragments: constant per thread across all bodies -> registers
    bf16x8 w3r[2][2];
    #pragma unroll
    for (int lb = 0; lb < 2; lb++)
        #pragma unroll
        for (int s = 0; s < 2; s++)
            w3r[lb][s] = *(const bf16x8*)(wsu + U_W3B + (lb * 16 + m) * 64 + s * 32 + q * 8);

    v2f hi2[4];                     // own h pairs for fac
    {
        uint4 hv4 = *(const uint4*)(wsu + U_HJB + i * 32 + sub * 8);
        unsigned int hd[4] = {hv4.x, hv4.y, hv4.z, hv4.w};
        #pragma unroll
        for (int e = 0; e < 4; e++) { hi2[e].x = blo(hd[e]); hi2[e].y = bhi(hd[e]); }
    }
    f32x4 b2q[4];              // bias slice for MFMA C-init (unscaled)
    #pragma unroll
    for (int nb = 0; nb < 4; nb++) {
        float4 bv = *(const float4*)(ws + WS_BI2 + nb * 16 + q * 4);
        b2q[nb][0] = bv.x; b2q[nb][1] = bv.y; b2q[nb][2] = bv.z; b2q[nb][3] = bv.w;
    }
    // Ea = 2^(pre-scaled a_i): loop-invariant across all tiles, in registers
    v2f ea2[8];
    {
        const float* ap = ws + WS_AA + i * 64 + q * 8;
        #pragma unroll
        for (int s = 0; s < 2; s++) {
            float4 lo = *(const float4*)(ap + s * 32);
            float4 hi = *(const float4*)(ap + s * 32 + 4);
            ea2[s * 4 + 0].x = lo.x; ea2[s * 4 + 0].y = lo.y;
            ea2[s * 4 + 1].x = lo.z; ea2[s * 4 + 1].y = lo.w;
            ea2[s * 4 + 2].x = hi.x; ea2[s * 4 + 2].y = hi.y;
            ea2[s * 4 + 3].x = hi.z; ea2[s * 4 + 3].y = hi.w;
        }
    }
    v2f hiv2, ei2;             // (l=m, l=m+16) pairs for stage C
    hiv2.x = bf2f(wsu[U_HJB + i * 32 + m]);      hiv2.y = bf2f(wsu[U_HJB + i * 32 + 16 + m]);
    ei2.x = ws[WS_CI + i * 32 + m];              ei2.y = ws[WS_CI + i * 32 + 16 + m];
    const float aggi = ws[WS_AGG + i];
    const float sub0 = (sub == 0) ? 1.0f : 0.0f;

    // ---- streaming pointers + tile-0 prefetch ----
    const unsigned short* hp = wsu + U_HJB + (jw + (lane >> 2)) * 32 + sub * 8;
    const unsigned short* bp = wsu + U_BJB + (jw + m) * 64 + q * 8;
    const unsigned short* jp = wsu + U_JT + ((jw + q * 4) * 16 + m) * 8;

    uint4 hvA = *(const uint4*)hp;
    uint4 b0A = *(const uint4*)bp;
    uint4 b1A = *(const uint4*)(bp + 32);
    uint4 hvB, b0B, b1B;
    __syncthreads();

    // persistent accumulators
    f32x4 accK[2];
    #pragma unroll
    for (int lb = 0; lb < 2; lb++) { accK[lb][0]=0.f; accK[lb][1]=0.f; accK[lb][2]=0.f; accK[lb][3]=0.f; }
    v2f u2; u2.x = 0.f; u2.y = 0.f;
    v2f vv2; vv2.x = 0.f; vv2.y = 0.f;
    float sumfac = 0.f;

    unsigned short* xb0 = &x2ls[w * 2 * 1152];
    unsigned short* xb1 = xb0 + 1152;

    auto stageB = [&](const unsigned short* xb) {
        bf16x8 x2f[2];
        #pragma unroll
        for (int s = 0; s < 2; s++)
            x2f[s] = *(const bf16x8*)(&xb[m * 72 + s * 32 + q * 8]);
        #pragma unroll
        for (int lb = 0; lb < 2; lb++) {
            #pragma unroll
            for (int s = 0; s < 2; s++) {
                accK[lb] = __builtin_amdgcn_mfma_f32_16x16x32_bf16(x2f[s], w3r[lb][s], accK[lb], 0, 0, 0);
            }
        }
    };

    auto body = [&](int T, uint4 hvc, uint4 b0c, uint4 b1c,
                    uint4& hvn, uint4& b0n, uint4& b1n,
                    unsigned short* xcur, const unsigned short* xprev) {
        // prefetch next tile's h/b
        hp += 2048; bp += 4096;
        hvn = *(const uint4*)hp;
        b0n = *(const uint4*)bp;
        b1n = *(const uint4*)(bp + 32);

        // jt loads for CURRENT tile issued at body TOP -- consumed at body
        // end (stage C); cover = stageB + fac + x1 + stageA
        uint4 jt4[4];
        #pragma unroll
        for (int r = 0; r < 4; r++) jt4[r] = *(const uint4*)(jp + r * 128);
        jp += 8192;

        // deferred stage B for previous tile (LDS data a full body old)
        if (T > 0) stageB(xprev);

        // 1) fac (lane owns j = T*64 + jw + (lane>>2)); zeroed at j==i
        float facm;
        {
            unsigned int hd[4] = {hvc.x, hvc.y, hvc.z, hvc.w};
            v2f s2v; s2v.x = 0.f; s2v.y = 0.f;
            #pragma unroll
            for (int e = 0; e < 4; e++) {
                v2f hj; hj.x = blo(hd[e]); hj.y = bhi(hd[e]);
                v2f d = hi2[e] - hj;
                s2v += d * d;                      // v_pk_fma
            }
            float s = s2v.x + s2v.y;
            s += __shfl_xor(s, 1); s += __shfl_xor(s, 2);
            int jj = T * 64 + jw + (lane >> 2);
            float facown = fminf(__builtin_amdgcn_rsqf(s), 2.0f) * aggi;
            facown = (jj == i) ? 0.0f : facown;
            sumfac = fmaf(sub0, facown, sumfac);
            facm = __shfl(facown, 4 * m);
        }

        // 2) x1 B-fragments: factored paired tanh (pk fma, shared rcp, NO exp2)
        bf16x8 afr[2];
        {
            unsigned int bd[8] = {b0c.x, b0c.y, b0c.z, b0c.w, b1c.x, b1c.y, b1c.z, b1c.w};
            #pragma unroll
            for (int s = 0; s < 2; s++) {
                union { uint4 u4; bf16x8 v; } pkd;
                #pragma unroll
                for (int e = 0; e < 4; e++) {
                    unsigned int bw = bd[s * 4 + e];
                    v2f eb; eb.x = blo(bw); eb.y = bhi(bw);
                    v2f t2 = tanh2_fact(ea2[s * 4 + e], eb);
                    ((unsigned int*)&pkd.u4)[e] = pk2(t2.x, t2.y);
                }
                afr[s] = pkd.v;
            }
        }

        // 3) stage A: X2^T = Wi2' * X1^T, C-init = bias (unscaled logit out)
        f32x4 accA[4];
        #pragma unroll
        for (int nb = 0; nb < 4; nb++) {
            f32x4 acc = b2q[nb];
            #pragma unroll
            for (int s = 0; s < 2; s++) {
                bf16x8 w2f = *(const bf16x8*)(&W2ls[(nb * 16 + m) * 72 + s * 32 + q * 8]);
                acc = __builtin_amdgcn_mfma_f32_16x16x32_bf16(w2f, afr[s], acc, 0, 0, 0);
            }
            accA[nb] = acc;
        }
        // epilogue A: x2s = facm * tanh(z) via Pade(15,6): z(15+z^2)/(15+6z^2)
        // |z| <= ~1.3 (6 sigma) -> abs err <= 2e-3, below bf16 store rounding.
        #pragma unroll
        for (int nb = 0; nb < 4; nb++) {
            v2f zA; zA.x = accA[nb][0]; zA.y = accA[nb][1];
            v2f zB; zB.x = accA[nb][2]; zB.y = accA[nb][3];
            v2f zzA = zA * zA, zzB = zB * zB;
            v2f nA = zA * (zzA + 15.0f), nB = zB * (zzB + 15.0f);
            v2f dA = zzA * 6.0f + 15.0f, dB = zzB * 6.0f + 15.0f;
            float rA = fast_rcp(dA.x * dA.y) * facm;   // fold fac into shared rcp
            float rB = fast_rcp(dB.x * dB.y) * facm;
            v2f swA; swA.x = dA.y; swA.y = dA.x;
            v2f swB; swB.x = dB.y; swB.y = dB.x;
            v2f tA = nA * (swA * rA);
            v2f tB = nB * (swB * rB);
            uint2 pk; pk.x = pk2(tA.x, tA.y); pk.y = pk2(tB.x, tB.y);
            *(uint2*)(&xcur[m * 72 + nb * 16 + q * 4]) = pk;
        }

        // 5) stage C: quantum partials; coh = rcp(1 + Ei*Ej) (pk fma, no exp2)
        #pragma unroll
        for (int r = 0; r < 4; r++) {
            uint4 jv = jt4[r];
            v2f hj2; hj2.x = blo(jv.x); hj2.y = bhi(jv.x);
            v2f ej2; ej2.x = blo(jv.y); ej2.y = bhi(jv.y);
            v2f pc2; pc2.x = blo(jv.z); pc2.y = bhi(jv.z);
            v2f ps2; ps2.x = blo(jv.w); ps2.y = bhi(jv.w);
            v2f dd = ei2 * ej2 + 1.0f;
            float rr = fast_rcp(dd.x * dd.y);
            v2f swd; swd.x = dd.y; swd.y = dd.x;
            v2f coh = swd * rr;                    // sigmoid of each element
            v2f cd = coh * (hiv2 - hj2);
            u2  += cd * pc2;
            vv2 += cd * ps2;
        }
    };

    #pragma unroll 1
    for (int T = 0; T < 16; T += 2) {
        body(T,     hvA, b0A, b1A, hvB, b0B, b1B, xb0, xb1);
        body(T + 1, hvB, b0B, b1B, hvA, b0A, b1A, xb1, xb0);
    }
    stageB(xb1);   // tile 15

    // ---- final reductions ----
    float T1[2];
    float aU[2] = {u2.x, u2.y};
    float aV[2] = {vv2.x, vv2.y};
    #pragma unroll
    for (int lb = 0; lb < 2; lb++) {
        T1[lb] = (accK[lb][0] + accK[lb][1]) + (accK[lb][2] + accK[lb][3]);
        T1[lb] += __shfl_xor(T1[lb], 16); T1[lb] += __shfl_xor(T1[lb], 32);
        aU[lb] += __shfl_xor(aU[lb], 16); aU[lb] += __shfl_xor(aU[lb], 32);
        aV[lb] += __shfl_xor(aV[lb], 16); aV[lb] += __shfl_xor(aV[lb], 32);
    }
    sumfac += __shfl_xor(sumfac, 1);  sumfac += __shfl_xor(sumfac, 2);
    sumfac += __shfl_xor(sumfac, 4);  sumfac += __shfl_xor(sumfac, 8);
    sumfac += __shfl_xor(sumfac, 16); sumfac += __shfl_xor(sumfac, 32);
    if (lane < 16) {
        redT[w][m] = T1[0];      redT[w][16 + m] = T1[1];
        redU[w][m] = aU[0];      redU[w][16 + m] = aU[1];
        redV[w][m] = aV[0];      redV[w][16 + m] = aV[1];
    }
    if (lane == 0) sfw[w] = sumfac;
    __syncthreads();
    if (tid < 32) {
        int l = tid;
        float t1 = (redT[0][l] + redT[1][l]) + (redT[2][l] + redT[3][l]);
        float uu = (redU[0][l] + redU[1][l]) + (redU[2][l] + redU[3][l]);
        float vvv = (redV[0][l] + redV[1][l]) + (redV[2][l] + redV[3][l]);
        float sf = (sfw[0] + sfw[1]) + (sfw[2] + sfw[3]);
        int mm = l & 15;
        uint2 jti = *(const uint2*)(wsu + U_JT + (i * 16 + mm) * 8 + 4);  // cc/sc pair words
        float pic = (l < 16) ? blo(jti.x) : bhi(jti.x);
        float pis = (l < 16) ? blo(jti.y) : bhi(jti.y);
        float isum = t1 + sf * ws[WS_BI3 + l] - (pic * uu + pis * vvv);
        out[i * 33 + l] = 0.5f * ws[WS_SELF + i * 32 + l] + 0.3f * isum;
        // parallel |isum| tail reduce
        float ab = fabsf(isum);
        ab += __shfl_xor(ab, 1); ab += __shfl_xor(ab, 2);
        ab += __shfl_xor(ab, 4); ab += __shfl_xor(ab, 8);
        ab += __shfl_xor(ab, 16);
        if (tid == 0) out[i * 33 + 32] = 0.1f + 0.05f * ab;
    }
}

extern "C" void kernel_launch(void* const* d_in, const int* in_sizes, int n_in,
                              void* d_out, int out_size, void* d_ws, size_t ws_size,
                              hipStream_t stream) {
    const float* state   = (const float*)d_in[0];
    const float* Ws1     = (const float*)d_in[1];
    const float* bs1     = (const float*)d_in[2];
    const float* Ws2     = (const float*)d_in[3];
    const float* bs2     = (const float*)d_in[4];
    const float* Ws3     = (const float*)d_in[5];
    const float* bs3     = (const float*)d_in[6];
    const float* Wi1     = (const float*)d_in[7];
    const float* bi1     = (const float*)d_in[8];
    const float* Wi2     = (const float*)d_in[9];
    const float* bi2     = (const float*)d_in[10];
    const float* Wi3     = (const float*)d_in[11];
    const float* bi3     = (const float*)d_in[12];
    const float* phase_w = (const float*)d_in[13];
    const float* Wc      = (const float*)d_in[14];
    const float* bc      = (const float*)d_in[15];
    const float* aggr    = (const float*)d_in[16];

    float* ws = (float*)d_ws;
    unsigned short* wsu = (unsigned short*)(ws + WS_FEND);
    float* out = (float*)d_out;

    precompute<<<256, 256, 0, stream>>>(state, Ws1, bs1, Ws2, bs2, Ws3, bs3,
                                        Wi1, bi1, Wi2, bi2, Wi3, bi3,
                                        phase_w, Wc, bc, aggr, ws, wsu);
    pair_kernel<<<NN, 256, 0, stream>>>(ws, wsu, out);
}